// Round 1
// baseline (693.272 us; speedup 1.0000x reference)
//
#include <hip/hip_runtime.h>
#include <math.h>

#define BATCHN 4
#define SEQL   4096
#define DMODEL 256
#define DIP    1576      // in-proj output cols
#define DINNER 512
#define DZCOLS 1024      // 2*D_INNER
#define CONVD  544
#define NHEADS 8
#define HDIM   64
#define DSTATE 16
#define CHK    64
#define NCHUNK 64
#define MROWS  (BATCHN*SEQL)

__device__ __forceinline__ float clip6f(float x) { return fminf(fmaxf(x, 0.0f), 6.0f); }

// ---------------------------------------------------------------------------
// K1: zx[M,1576] = x[M,256] @ W_in[256,1576]   (fp32, 128x128 tile, 8x8/thr)
// ---------------------------------------------------------------------------
__global__ __launch_bounds__(256) void k_gemm_in(const float* __restrict__ A,
                                                 const float* __restrict__ B,
                                                 float* __restrict__ C)
{
    __shared__ float As[8][132];
    __shared__ float Bs[8][132];
    const int m0 = blockIdx.y * 128;
    const int n0 = blockIdx.x * 128;
    const int t  = threadIdx.x;
    const int tx = t & 15, ty = t >> 4;
    const int ar = t >> 1, ak = (t & 1) * 4;
    const int bk = t >> 5, bn = (t & 31) * 4;
    float acc[8][8];
#pragma unroll
    for (int i = 0; i < 8; ++i)
#pragma unroll
        for (int j = 0; j < 8; ++j) acc[i][j] = 0.0f;

    for (int k0 = 0; k0 < 256; k0 += 8) {
        float4 av = *reinterpret_cast<const float4*>(A + (size_t)(m0 + ar) * 256 + k0 + ak);
        As[ak + 0][ar] = av.x;
        As[ak + 1][ar] = av.y;
        As[ak + 2][ar] = av.z;
        As[ak + 3][ar] = av.w;
        float4 bv = make_float4(0.f, 0.f, 0.f, 0.f);
        if (n0 + bn < DIP)
            bv = *reinterpret_cast<const float4*>(B + (size_t)(k0 + bk) * DIP + n0 + bn);
        *reinterpret_cast<float4*>(&Bs[bk][bn]) = bv;
        __syncthreads();
#pragma unroll
        for (int kk = 0; kk < 8; ++kk) {
            float4 a0 = *reinterpret_cast<const float4*>(&As[kk][ty * 8]);
            float4 a1 = *reinterpret_cast<const float4*>(&As[kk][ty * 8 + 4]);
            float4 b0 = *reinterpret_cast<const float4*>(&Bs[kk][tx * 8]);
            float4 b1 = *reinterpret_cast<const float4*>(&Bs[kk][tx * 8 + 4]);
            float a[8]  = {a0.x, a0.y, a0.z, a0.w, a1.x, a1.y, a1.z, a1.w};
            float bb[8] = {b0.x, b0.y, b0.z, b0.w, b1.x, b1.y, b1.z, b1.w};
#pragma unroll
            for (int i = 0; i < 8; ++i)
#pragma unroll
                for (int j = 0; j < 8; ++j)
                    acc[i][j] = fmaf(a[i], bb[j], acc[i][j]);
        }
        __syncthreads();
    }
#pragma unroll
    for (int i = 0; i < 8; ++i) {
        const int row = m0 + ty * 8 + i;
#pragma unroll
        for (int j = 0; j < 8; ++j) {
            const int col = n0 + tx * 8 + j;
            if (col < DIP) C[(size_t)row * DIP + col] = acc[i][j];
        }
    }
}

// ---------------------------------------------------------------------------
// K2: causal conv1d (K=4) over xBC cols of zx, relu6, -> convout[M,544]
// ---------------------------------------------------------------------------
__global__ __launch_bounds__(256) void k_conv(const float* __restrict__ zx,
                                              const float* __restrict__ conv_w,
                                              const float* __restrict__ conv_b,
                                              const float* __restrict__ init_conv,
                                              float* __restrict__ convout)
{
    const int NC4 = CONVD / 4; // 136
    int gid = blockIdx.x * 256 + threadIdx.x;
    if (gid >= MROWS * NC4) return;
    const int row  = gid / NC4;
    const int c    = (gid % NC4) * 4;
    const int b    = row / SEQL;
    const int tpos = row % SEQL;
    float4 acc = *reinterpret_cast<const float4*>(conv_b + c);
#pragma unroll
    for (int j = 0; j < 4; ++j) {
        const int srct = tpos - 3 + j;
        float4 v;
        if (srct >= 0)
            v = *reinterpret_cast<const float4*>(zx + (size_t)(b * SEQL + srct) * DIP + DZCOLS + c);
        else
            v = *reinterpret_cast<const float4*>(init_conv + (size_t)(tpos + 1 + j) * CONVD + c);
        const float4 w = *reinterpret_cast<const float4*>(conv_w + (size_t)j * CONVD + c);
        acc.x = fmaf(w.x, v.x, acc.x);
        acc.y = fmaf(w.y, v.y, acc.y);
        acc.z = fmaf(w.z, v.z, acc.z);
        acc.w = fmaf(w.w, v.w, acc.w);
    }
    acc.x = clip6f(acc.x); acc.y = clip6f(acc.y);
    acc.z = clip6f(acc.z); acc.w = clip6f(acc.w);
    *reinterpret_cast<float4*>(convout + (size_t)row * CONVD + c) = acc;
}

// ---------------------------------------------------------------------------
// K3: per (b,h,chunk): A_cum (complex wave scan), chunk totals, local states
//     st[b,c,h,p,n] = sum_l B[l,n] * dt[l] * exp(ct - cum[l]) * x[l,p]
// ---------------------------------------------------------------------------
__global__ __launch_bounds__(256) void k_states(const float* __restrict__ zx,
                                                const float* __restrict__ conv,
                                                const float* __restrict__ A_log,
                                                const float* __restrict__ dt_bias,
                                                float* __restrict__ Acum,
                                                float* __restrict__ ctbuf,
                                                float* __restrict__ st)
{
    const int c = blockIdx.x, h = blockIdx.y, b = blockIdx.z;
    __shared__ float wr[CHK], wi[CHK];
    __shared__ float xs[CHK][HDIM];
    __shared__ float Bsh[CHK][DSTATE];
    const int t = threadIdx.x;

    // cooperative tile loads (independent of wave-0 scan below)
#pragma unroll
    for (int q = 0; q < 4; ++q) {
        const int g = t + q * 256;
        const int l = g >> 4, p4 = (g & 15) * 4;
        const float4 v = *reinterpret_cast<const float4*>(
            conv + (size_t)(b * SEQL + c * CHK + l) * CONVD + h * HDIM + p4);
        xs[l][p4 + 0] = v.x; xs[l][p4 + 1] = v.y; xs[l][p4 + 2] = v.z; xs[l][p4 + 3] = v.w;
    }
    {
        const int l = t >> 2, n4 = (t & 3) * 4;
        const float4 v = *reinterpret_cast<const float4*>(
            conv + (size_t)(b * SEQL + c * CHK + l) * CONVD + DINNER + n4);
        Bsh[l][n4 + 0] = v.x; Bsh[l][n4 + 1] = v.y; Bsh[l][n4 + 2] = v.z; Bsh[l][n4 + 3] = v.w;
    }

    if (t < 64) {
        const int l = t;
        const int row = b * SEQL + c * CHK + l;
        const float dtv = fminf(expf(zx[(size_t)row * DIP + 1568 + h] + dt_bias[h]), 6.0f);
        const float Ar = -expf(A_log[2 * h]);
        const float Ai = A_log[2 * h + 1];
        float cr = Ar * dtv, ci = Ai * dtv;
#pragma unroll
        for (int off = 1; off < 64; off <<= 1) {
            const float pr = __shfl_up(cr, off);
            const float pi = __shfl_up(ci, off);
            if (l >= off) { cr += pr; ci += pi; }
        }
        const size_t aidx = ((((size_t)b * NHEADS + h) * NCHUNK + c) * CHK + l) * 2;
        Acum[aidx] = cr; Acum[aidx + 1] = ci;
        const float ctr = __shfl(cr, 63), cti = __shfl(ci, 63);
        if (l == 63) {
            const size_t ci2 = (((size_t)b * NHEADS + h) * NCHUNK + c) * 2;
            ctbuf[ci2] = ctr; ctbuf[ci2 + 1] = cti;
        }
        const float e = expf(ctr - cr);
        float sn, cn; sincosf(cti - ci, &sn, &cn);
        wr[l] = e * cn * dtv;
        wi[l] = e * sn * dtv;
    }
    __syncthreads();

    const int p = t >> 2, n0 = (t & 3) * 4;
    float accr[4] = {0.f, 0.f, 0.f, 0.f};
    float acci[4] = {0.f, 0.f, 0.f, 0.f};
    for (int l = 0; l < CHK; ++l) {
        const float xv = xs[l][p];
        const float xr = xv * wr[l];
        const float xi = xv * wi[l];
#pragma unroll
        for (int j = 0; j < 4; ++j) {
            const float bb = Bsh[l][n0 + j];
            accr[j] = fmaf(bb, xr, accr[j]);
            acci[j] = fmaf(bb, xi, acci[j]);
        }
    }
    const size_t sidx = (((((size_t)b * NCHUNK + c) * NHEADS + h) * HDIM + p) * DSTATE + n0) * 2;
    float4 o0 = make_float4(accr[0], acci[0], accr[1], acci[1]);
    float4 o1 = make_float4(accr[2], acci[2], accr[3], acci[3]);
    *reinterpret_cast<float4*>(st + sidx)     = o0;
    *reinterpret_cast<float4*>(st + sidx + 4) = o1;
}

// ---------------------------------------------------------------------------
// K4: sequential inter-chunk complex scan; writes state ENTERING each chunk
// ---------------------------------------------------------------------------
__global__ __launch_bounds__(1024) void k_scan(const float* __restrict__ ctbuf,
                                               const float* __restrict__ st,
                                               const float* __restrict__ init_ssm,
                                               float* __restrict__ Sin)
{
    const int h = blockIdx.x, b = blockIdx.y;
    __shared__ float Tr[NCHUNK], Ti[NCHUNK];
    const int t = threadIdx.x;
    if (t < NCHUNK) {
        const size_t ci2 = (((size_t)b * NHEADS + h) * NCHUNK + t) * 2;
        const float e = expf(ctbuf[ci2]);
        float sn, cn; sincosf(ctbuf[ci2 + 1], &sn, &cn);
        Tr[t] = e * cn; Ti[t] = e * sn;
    }
    __syncthreads();
    const int p = t >> 4, n = t & 15;
    const size_t ii = (((size_t)h * HDIM + p) * DSTATE + n) * 2;
    float Sr = init_ssm[ii], Si = init_ssm[ii + 1];
    for (int z = 0; z < NCHUNK; ++z) {
        const size_t idx = (((((size_t)b * NCHUNK + z) * NHEADS + h) * HDIM + p) * DSTATE + n) * 2;
        Sin[idx] = Sr; Sin[idx + 1] = Si;
        const float sr = st[idx], si = st[idx + 1];
        const float tr = Tr[z], ti = Ti[z];
        const float nr = fmaf(tr, Sr, fmaf(-ti, Si, sr));
        const float ni = fmaf(tr, Si, fmaf(ti, Sr, si));
        Sr = nr; Si = ni;
    }
}

// ---------------------------------------------------------------------------
// K5: per (b,h,chunk): Y = G @ xdt + exp(A_cum)*(C . S_in); D residual;
//     gate with clip6(z); write yz IN-PLACE over z columns of zx.
// ---------------------------------------------------------------------------
__global__ __launch_bounds__(256) void k_yout(const float* __restrict__ conv,
                                              const float* __restrict__ Acum,
                                              const float* __restrict__ Sin,
                                              const float* __restrict__ Dp,
                                              const float* __restrict__ dt_bias,
                                              float* __restrict__ zx)
{
    const int c = blockIdx.x, h = blockIdx.y, b = blockIdx.z;
    __shared__ float xdt[CHK][HDIM];          // 16 KB
    __shared__ float Gr[CHK][CHK + 1];        // 16.6 KB
    __shared__ float Gi[CHK][CHK + 1];        // 16.6 KB
    __shared__ float Bsh[CHK][DSTATE + 1];    // 4.35 KB
    __shared__ float Csh[CHK][DSTATE + 1];    // 4.35 KB
    __shared__ float cumr[CHK], cumi[CHK], Er[CHK], Ei[CHK], dts[CHK];
    const int t = threadIdx.x;

    if (t < 64) {
        const int l = t;
        const int row = b * SEQL + c * CHK + l;
        dts[l] = fminf(expf(zx[(size_t)row * DIP + 1568 + h] + dt_bias[h]), 6.0f);
        const size_t aidx = ((((size_t)b * NHEADS + h) * NCHUNK + c) * CHK + l) * 2;
        const float cr = Acum[aidx], ci = Acum[aidx + 1];
        cumr[l] = cr; cumi[l] = ci;
        const float e = expf(cr);
        float sn, cn; sincosf(ci, &sn, &cn);
        Er[l] = e * cn; Ei[l] = e * sn;
    }
    __syncthreads();

#pragma unroll
    for (int q = 0; q < 4; ++q) {
        const int g = t + q * 256;
        const int l = g >> 4, p4 = (g & 15) * 4;
        const float4 v = *reinterpret_cast<const float4*>(
            conv + (size_t)(b * SEQL + c * CHK + l) * CONVD + h * HDIM + p4);
        const float d = dts[l];
        xdt[l][p4 + 0] = v.x * d; xdt[l][p4 + 1] = v.y * d;
        xdt[l][p4 + 2] = v.z * d; xdt[l][p4 + 3] = v.w * d;
    }
    {
        const int l = t >> 2, n4 = (t & 3) * 4;
        const float* cp = conv + (size_t)(b * SEQL + c * CHK + l) * CONVD;
        const float4 bv = *reinterpret_cast<const float4*>(cp + DINNER + n4);
        const float4 cv = *reinterpret_cast<const float4*>(cp + DINNER + DSTATE + n4);
        Bsh[l][n4 + 0] = bv.x; Bsh[l][n4 + 1] = bv.y; Bsh[l][n4 + 2] = bv.z; Bsh[l][n4 + 3] = bv.w;
        Csh[l][n4 + 0] = cv.x; Csh[l][n4 + 1] = cv.y; Csh[l][n4 + 2] = cv.z; Csh[l][n4 + 3] = cv.w;
    }
    __syncthreads();

    // build G = (C.B^T) * exp(segsum)  (lower triangular incl diagonal)
#pragma unroll
    for (int q = 0; q < 16; ++q) {
        const int g = t + q * 256;
        const int l = g >> 6, s = g & 63;
        float vr = 0.f, vi = 0.f;
        if (s <= l) {
            float dot = 0.f;
#pragma unroll
            for (int n = 0; n < DSTATE; ++n) dot += Csh[l][n] * Bsh[s][n];
            const float e = expf(cumr[l] - cumr[s]);
            float sn, cn; sincosf(cumi[l] - cumi[s], &sn, &cn);
            vr = dot * e * cn;
            vi = dot * e * sn;
        }
        Gr[l][s] = vr; Gi[l][s] = vi;
    }
    __syncthreads();

    const int tx = t & 15, ty = t >> 4;
    float accr[4][4], acci[4][4];
#pragma unroll
    for (int i = 0; i < 4; ++i)
#pragma unroll
        for (int j = 0; j < 4; ++j) { accr[i][j] = 0.f; acci[i][j] = 0.f; }

    const int send = (((int)(t >> 6)) + 1) * 16;  // wave-uniform triangular bound
    for (int s = 0; s < send; ++s) {
        const float4 xq = *reinterpret_cast<const float4*>(&xdt[s][tx * 4]);
        const float xv[4] = {xq.x, xq.y, xq.z, xq.w};
#pragma unroll
        for (int i = 0; i < 4; ++i) {
            const int l = ty * 4 + i;
            const float gr = Gr[l][s], gi = Gi[l][s];
#pragma unroll
            for (int j = 0; j < 4; ++j) {
                accr[i][j] = fmaf(gr, xv[j], accr[i][j]);
                acci[i][j] = fmaf(gi, xv[j], acci[i][j]);
            }
        }
    }

    const float* SinB = Sin + ((((size_t)b * NCHUNK + c) * NHEADS + h) * HDIM) * DSTATE * 2;
    const float dcoef = Dp[2 * h];
#pragma unroll
    for (int j = 0; j < 4; ++j) {
        const int p = tx * 4 + j;
        float sv[32];
        const float4* sp = reinterpret_cast<const float4*>(SinB + (size_t)p * DSTATE * 2);
#pragma unroll
        for (int q = 0; q < 8; ++q) {
            const float4 v4 = sp[q];
            sv[q * 4 + 0] = v4.x; sv[q * 4 + 1] = v4.y; sv[q * 4 + 2] = v4.z; sv[q * 4 + 3] = v4.w;
        }
#pragma unroll
        for (int i = 0; i < 4; ++i) {
            const int l = ty * 4 + i;
            float Or = 0.f, Oi = 0.f;
#pragma unroll
            for (int n = 0; n < DSTATE; ++n) {
                const float cv = Csh[l][n];
                Or = fmaf(cv, sv[2 * n], Or);
                Oi = fmaf(cv, sv[2 * n + 1], Oi);
            }
            const float er = Er[l], ei = Ei[l];
            float yr = accr[i][j] + er * Or - ei * Oi;
            float yi = acci[i][j] + er * Oi + ei * Or;
            const int row = b * SEQL + c * CHK + l;
            const float xinv = conv[(size_t)row * CONVD + h * HDIM + p];
            yr = fmaf(xinv, dcoef, yr);
            const size_t zidx = (size_t)row * DIP + h * 128 + p;
            const float zr = zx[zidx], zi2 = zx[zidx + 64];
            zx[zidx]      = yr * clip6f(zr);
            zx[zidx + 64] = yi * clip6f(zi2);
        }
    }
}

// ---------------------------------------------------------------------------
// K6a: per-row RMS scale over the 1024 yz columns (in zx)
// ---------------------------------------------------------------------------
__global__ __launch_bounds__(256) void k_rms(const float* __restrict__ zx,
                                             float* __restrict__ scale)
{
    const int w = threadIdx.x >> 6, lane = threadIdx.x & 63;
    const int row = blockIdx.x * 4 + w;
    const float* p = zx + (size_t)row * DIP;
    float ss = 0.f;
#pragma unroll
    for (int q = 0; q < 4; ++q) {
        const float4 v = *reinterpret_cast<const float4*>(p + lane * 4 + q * 256);
        ss += v.x * v.x + v.y * v.y + v.z * v.z + v.w * v.w;
    }
#pragma unroll
    for (int off = 32; off > 0; off >>= 1) ss += __shfl_down(ss, off);
    if (lane == 0) scale[row] = rsqrtf(ss * (1.0f / 1024.0f) + 1e-5f);
}

// ---------------------------------------------------------------------------
// K6b: out[M,256] = (yz * scale_row * norm_w_k) @ W_out[1024,256]
// ---------------------------------------------------------------------------
__global__ __launch_bounds__(256) void k_gemm_out(const float* __restrict__ Azx,
                                                  const float* __restrict__ Wout,
                                                  const float* __restrict__ scale,
                                                  const float* __restrict__ normw,
                                                  float* __restrict__ out)
{
    __shared__ float As[8][132];
    __shared__ float Bs[8][132];
    const int m0 = blockIdx.y * 128;
    const int n0 = blockIdx.x * 128;
    const int t  = threadIdx.x;
    const int tx = t & 15, ty = t >> 4;
    const int ar = t >> 1, ak = (t & 1) * 4;
    const int bk = t >> 5, bn = (t & 31) * 4;
    float acc[8][8];
#pragma unroll
    for (int i = 0; i < 8; ++i)
#pragma unroll
        for (int j = 0; j < 8; ++j) acc[i][j] = 0.0f;

    const float sc = scale[m0 + ar];
    for (int k0 = 0; k0 < DZCOLS; k0 += 8) {
        float4 av = *reinterpret_cast<const float4*>(Azx + (size_t)(m0 + ar) * DIP + k0 + ak);
        As[ak + 0][ar] = av.x * sc;
        As[ak + 1][ar] = av.y * sc;
        As[ak + 2][ar] = av.z * sc;
        As[ak + 3][ar] = av.w * sc;
        float4 bv = *reinterpret_cast<const float4*>(Wout + (size_t)(k0 + bk) * DMODEL + n0 + bn);
        const float nw = normw[k0 + bk];
        bv.x *= nw; bv.y *= nw; bv.z *= nw; bv.w *= nw;
        *reinterpret_cast<float4*>(&Bs[bk][bn]) = bv;
        __syncthreads();
#pragma unroll
        for (int kk = 0; kk < 8; ++kk) {
            float4 a0 = *reinterpret_cast<const float4*>(&As[kk][ty * 8]);
            float4 a1 = *reinterpret_cast<const float4*>(&As[kk][ty * 8 + 4]);
            float4 b0 = *reinterpret_cast<const float4*>(&Bs[kk][tx * 8]);
            float4 b1 = *reinterpret_cast<const float4*>(&Bs[kk][tx * 8 + 4]);
            float a[8]  = {a0.x, a0.y, a0.z, a0.w, a1.x, a1.y, a1.z, a1.w};
            float bb[8] = {b0.x, b0.y, b0.z, b0.w, b1.x, b1.y, b1.z, b1.w};
#pragma unroll
            for (int i = 0; i < 8; ++i)
#pragma unroll
                for (int j = 0; j < 8; ++j)
                    acc[i][j] = fmaf(a[i], bb[j], acc[i][j]);
        }
        __syncthreads();
    }
#pragma unroll
    for (int i = 0; i < 8; ++i) {
        const int row = m0 + ty * 8 + i;
#pragma unroll
        for (int j = 0; j < 8; ++j) {
            const int col = n0 + tx * 8 + j;
            out[(size_t)row * DMODEL + col] = acc[i][j];
        }
    }
}

// ---------------------------------------------------------------------------
extern "C" void kernel_launch(void* const* d_in, const int* in_sizes, int n_in,
                              void* d_out, int out_size, void* d_ws, size_t ws_size,
                              hipStream_t stream)
{
    const float* x         = (const float*)d_in[0];
    const float* W_in      = (const float*)d_in[1];
    const float* conv_w    = (const float*)d_in[2];
    const float* conv_b    = (const float*)d_in[3];
    const float* A_log     = (const float*)d_in[4];
    const float* dt_bias   = (const float*)d_in[5];
    const float* Dp        = (const float*)d_in[6];
    const float* init_conv = (const float*)d_in[7];
    const float* init_ssm  = (const float*)d_in[8];
    const float* norm_w    = (const float*)d_in[9];
    const float* W_out     = (const float*)d_in[10];
    float* out = (float*)d_out;

    float* ws      = (float*)d_ws;
    float* zx      = ws;                                   // M*1576   = 25,821,184 f
    float* convout = zx + (size_t)MROWS * DIP;             // M*544    =  8,912,896 f
    float* Acum    = convout + (size_t)MROWS * CONVD;      // 262,144 f
    float* ctbuf   = Acum + (size_t)BATCHN * NHEADS * NCHUNK * CHK * 2;   // 4096 f
    float* stbuf   = ctbuf + (size_t)BATCHN * NHEADS * NCHUNK * 2;        // 4,194,304 f
    float* SinBuf  = stbuf + (size_t)BATCHN * NCHUNK * NHEADS * HDIM * DSTATE * 2; // 4,194,304 f
    float* scaleb  = SinBuf + (size_t)BATCHN * NCHUNK * NHEADS * HDIM * DSTATE * 2; // 16,384 f
    // total ~173.6 MB of workspace

    k_gemm_in<<<dim3(13, 128), dim3(256), 0, stream>>>(x, W_in, zx);

    const int convThreads = MROWS * (CONVD / 4);
    k_conv<<<(convThreads + 255) / 256, dim3(256), 0, stream>>>(zx, conv_w, conv_b, init_conv, convout);

    k_states<<<dim3(NCHUNK, NHEADS, BATCHN), dim3(256), 0, stream>>>(
        zx, convout, A_log, dt_bias, Acum, ctbuf, stbuf);

    k_scan<<<dim3(NHEADS, BATCHN), dim3(1024), 0, stream>>>(ctbuf, stbuf, init_ssm, SinBuf);

    k_yout<<<dim3(NCHUNK, NHEADS, BATCHN), dim3(256), 0, stream>>>(
        convout, Acum, SinBuf, Dp, dt_bias, zx);

    k_rms<<<dim3(MROWS / 4), dim3(256), 0, stream>>>(zx, scaleb);

    k_gemm_out<<<dim3(2, 128), dim3(256), 0, stream>>>(zx, W_out, scaleb, norm_w, out);
}

// Round 2
// 346.666 us; speedup vs baseline: 1.9998x; 1.9998x over previous
//
#include <hip/hip_runtime.h>
#include <math.h>

#define BATCHN 4
#define SEQL   4096
#define DMODEL 256
#define DIP    1576      // in-proj output cols
#define DINNER 512
#define DZCOLS 1024      // 2*D_INNER
#define CONVD  544
#define NHEADS 8
#define HDIM   64
#define DSTATE 16
#define CHK    64
#define NCHUNK 64
#define MROWS  (BATCHN*SEQL)
#define NPAD   1664      // 13*128, padded N for in-proj GEMM

typedef _Float16 half8 __attribute__((ext_vector_type(8)));
typedef short    s16x8 __attribute__((ext_vector_type(8)));
typedef float    f32x4 __attribute__((ext_vector_type(4)));

__device__ __forceinline__ float clip6f(float x) { return fminf(fmaxf(x, 0.0f), 6.0f); }

// ---------------------------------------------------------------------------
// conversions to fp16
// ---------------------------------------------------------------------------
__global__ __launch_bounds__(256) void k_cvt_x(const float* __restrict__ X,
                                               _Float16* __restrict__ A)
{
    const int gid = blockIdx.x * 256 + threadIdx.x;   // M*256/8 threads
    const float4 a = *reinterpret_cast<const float4*>(X + (size_t)gid * 8);
    const float4 b = *reinterpret_cast<const float4*>(X + (size_t)gid * 8 + 4);
    half8 h;
    h[0] = (_Float16)a.x; h[1] = (_Float16)a.y; h[2] = (_Float16)a.z; h[3] = (_Float16)a.w;
    h[4] = (_Float16)b.x; h[5] = (_Float16)b.y; h[6] = (_Float16)b.z; h[7] = (_Float16)b.w;
    *reinterpret_cast<half8*>(A + (size_t)gid * 8) = h;
}

// W_in[256,1576] -> Bt[1664,256] fp16 (zero pad n>=1576)
__global__ __launch_bounds__(256) void k_cvt_win(const float* __restrict__ W,
                                                 _Float16* __restrict__ Bt)
{
    const int gid = blockIdx.x * 256 + threadIdx.x;   // NPAD*256 threads
    const int k = gid & 255, n = gid >> 8;
    const float v = (n < DIP) ? W[(size_t)k * DIP + n] : 0.0f;
    Bt[gid] = (_Float16)v;
}

// W_out[1024,256]*norm_w[k] -> Wot[256,1024] fp16
__global__ __launch_bounds__(256) void k_cvt_wout(const float* __restrict__ W,
                                                  const float* __restrict__ nw,
                                                  _Float16* __restrict__ Bt)
{
    const int gid = blockIdx.x * 256 + threadIdx.x;   // 256*1024 threads
    const int k = gid & 1023, n = gid >> 10;
    Bt[gid] = (_Float16)(W[(size_t)k * DMODEL + n] * nw[k]);
}

// ---------------------------------------------------------------------------
// fp16 MFMA GEMM: C[M,ldc] (fp32) = A[M,KTOT] @ Bt[N,KTOT]^T
// 128x128 tile, BK=64, 4 waves, each wave 64x64 out (4x4 frags of 16x16x32)
// ---------------------------------------------------------------------------
template<int KTOT, bool NGUARD, bool SCALE>
__global__ __launch_bounds__(256) void k_gemm16(const _Float16* __restrict__ A,
                                                const _Float16* __restrict__ Bt,
                                                float* __restrict__ C,
                                                const int ldc, const int ncols,
                                                const float* __restrict__ scale)
{
    __shared__ _Float16 As[128][72];
    __shared__ _Float16 Bs[128][72];
    const int t  = threadIdx.x;
    const int m0 = blockIdx.y * 128;
    const int n0 = blockIdx.x * 128;
    const int lane = t & 63, wid = t >> 6;
    const int wr = wid >> 1, wc = wid & 1;
    const int fr = lane & 15, fq = lane >> 4;

    f32x4 acc[4][4];
#pragma unroll
    for (int m = 0; m < 4; ++m)
#pragma unroll
        for (int n = 0; n < 4; ++n)
#pragma unroll
            for (int e = 0; e < 4; ++e) acc[m][n][e] = 0.0f;

    for (int kt = 0; kt < KTOT; kt += 64) {
#pragma unroll
        for (int q = 0; q < 4; ++q) {
            const int idx = t + q * 256;
            const int r = idx >> 3, ch = idx & 7;
            *reinterpret_cast<s16x8*>(&As[r][ch * 8]) =
                *reinterpret_cast<const s16x8*>(A + (size_t)(m0 + r) * KTOT + kt + ch * 8);
            *reinterpret_cast<s16x8*>(&Bs[r][ch * 8]) =
                *reinterpret_cast<const s16x8*>(Bt + (size_t)(n0 + r) * KTOT + kt + ch * 8);
        }
        __syncthreads();
#pragma unroll
        for (int ks = 0; ks < 64; ks += 32) {
            half8 af[4], bf[4];
#pragma unroll
            for (int m = 0; m < 4; ++m)
                af[m] = *reinterpret_cast<const half8*>(&As[wr * 64 + m * 16 + fr][ks + fq * 8]);
#pragma unroll
            for (int n = 0; n < 4; ++n)
                bf[n] = *reinterpret_cast<const half8*>(&Bs[wc * 64 + n * 16 + fr][ks + fq * 8]);
#pragma unroll
            for (int m = 0; m < 4; ++m)
#pragma unroll
                for (int n = 0; n < 4; ++n)
                    acc[m][n] = __builtin_amdgcn_mfma_f32_16x16x32_f16(af[m], bf[n], acc[m][n], 0, 0, 0);
        }
        __syncthreads();
    }

#pragma unroll
    for (int m = 0; m < 4; ++m)
#pragma unroll
        for (int j = 0; j < 4; ++j) {
            const int row = m0 + wr * 64 + m * 16 + fq * 4 + j;
            const float sc = SCALE ? scale[row] : 1.0f;
#pragma unroll
            for (int n = 0; n < 4; ++n) {
                const int col = n0 + wc * 64 + n * 16 + fr;
                if (!NGUARD || col < ncols)
                    C[(size_t)row * ldc + col] = acc[m][n][j] * sc;
            }
        }
}

// ---------------------------------------------------------------------------
// K2: causal conv1d (K=4) over xBC cols of zx, relu6, -> convout[M,544]
// ---------------------------------------------------------------------------
__global__ __launch_bounds__(256) void k_conv(const float* __restrict__ zx,
                                              const float* __restrict__ conv_w,
                                              const float* __restrict__ conv_b,
                                              const float* __restrict__ init_conv,
                                              float* __restrict__ convout)
{
    const int NC4 = CONVD / 4; // 136
    int gid = blockIdx.x * 256 + threadIdx.x;
    if (gid >= MROWS * NC4) return;
    const int row  = gid / NC4;
    const int c    = (gid % NC4) * 4;
    const int b    = row / SEQL;
    const int tpos = row % SEQL;
    float4 acc = *reinterpret_cast<const float4*>(conv_b + c);
#pragma unroll
    for (int j = 0; j < 4; ++j) {
        const int srct = tpos - 3 + j;
        float4 v;
        if (srct >= 0)
            v = *reinterpret_cast<const float4*>(zx + (size_t)(b * SEQL + srct) * DIP + DZCOLS + c);
        else
            v = *reinterpret_cast<const float4*>(init_conv + (size_t)(tpos + 1 + j) * CONVD + c);
        const float4 w = *reinterpret_cast<const float4*>(conv_w + (size_t)j * CONVD + c);
        acc.x = fmaf(w.x, v.x, acc.x);
        acc.y = fmaf(w.y, v.y, acc.y);
        acc.z = fmaf(w.z, v.z, acc.z);
        acc.w = fmaf(w.w, v.w, acc.w);
    }
    acc.x = clip6f(acc.x); acc.y = clip6f(acc.y);
    acc.z = clip6f(acc.z); acc.w = clip6f(acc.w);
    *reinterpret_cast<float4*>(convout + (size_t)row * CONVD + c) = acc;
}

// ---------------------------------------------------------------------------
// K3: per (b,h,chunk): A_cum (complex wave scan), chunk totals, local states
// ---------------------------------------------------------------------------
__global__ __launch_bounds__(256) void k_states(const float* __restrict__ zx,
                                                const float* __restrict__ conv,
                                                const float* __restrict__ A_log,
                                                const float* __restrict__ dt_bias,
                                                float* __restrict__ Acum,
                                                float* __restrict__ ctbuf,
                                                float* __restrict__ st)
{
    const int c = blockIdx.x, h = blockIdx.y, b = blockIdx.z;
    __shared__ float wr[CHK], wi[CHK];
    __shared__ float xs[CHK][HDIM];
    __shared__ float Bsh[CHK][DSTATE];
    const int t = threadIdx.x;

#pragma unroll
    for (int q = 0; q < 4; ++q) {
        const int g = t + q * 256;
        const int l = g >> 4, p4 = (g & 15) * 4;
        const float4 v = *reinterpret_cast<const float4*>(
            conv + (size_t)(b * SEQL + c * CHK + l) * CONVD + h * HDIM + p4);
        xs[l][p4 + 0] = v.x; xs[l][p4 + 1] = v.y; xs[l][p4 + 2] = v.z; xs[l][p4 + 3] = v.w;
    }
    {
        const int l = t >> 2, n4 = (t & 3) * 4;
        const float4 v = *reinterpret_cast<const float4*>(
            conv + (size_t)(b * SEQL + c * CHK + l) * CONVD + DINNER + n4);
        Bsh[l][n4 + 0] = v.x; Bsh[l][n4 + 1] = v.y; Bsh[l][n4 + 2] = v.z; Bsh[l][n4 + 3] = v.w;
    }

    if (t < 64) {
        const int l = t;
        const int row = b * SEQL + c * CHK + l;
        const float dtv = fminf(expf(zx[(size_t)row * DIP + 1568 + h] + dt_bias[h]), 6.0f);
        const float Ar = -expf(A_log[2 * h]);
        const float Ai = A_log[2 * h + 1];
        float cr = Ar * dtv, ci = Ai * dtv;
#pragma unroll
        for (int off = 1; off < 64; off <<= 1) {
            const float pr = __shfl_up(cr, off);
            const float pi = __shfl_up(ci, off);
            if (l >= off) { cr += pr; ci += pi; }
        }
        const size_t aidx = ((((size_t)b * NHEADS + h) * NCHUNK + c) * CHK + l) * 2;
        Acum[aidx] = cr; Acum[aidx + 1] = ci;
        const float ctr = __shfl(cr, 63), cti = __shfl(ci, 63);
        if (l == 63) {
            const size_t ci2 = (((size_t)b * NHEADS + h) * NCHUNK + c) * 2;
            ctbuf[ci2] = ctr; ctbuf[ci2 + 1] = cti;
        }
        const float e = expf(ctr - cr);
        float sn, cn; sincosf(cti - ci, &sn, &cn);
        wr[l] = e * cn * dtv;
        wi[l] = e * sn * dtv;
    }
    __syncthreads();

    const int p = t >> 2, n0 = (t & 3) * 4;
    float accr[4] = {0.f, 0.f, 0.f, 0.f};
    float acci[4] = {0.f, 0.f, 0.f, 0.f};
    for (int l = 0; l < CHK; ++l) {
        const float xv = xs[l][p];
        const float xr = xv * wr[l];
        const float xi = xv * wi[l];
#pragma unroll
        for (int j = 0; j < 4; ++j) {
            const float bb = Bsh[l][n0 + j];
            accr[j] = fmaf(bb, xr, accr[j]);
            acci[j] = fmaf(bb, xi, acci[j]);
        }
    }
    const size_t sidx = (((((size_t)b * NCHUNK + c) * NHEADS + h) * HDIM + p) * DSTATE + n0) * 2;
    float4 o0 = make_float4(accr[0], acci[0], accr[1], acci[1]);
    float4 o1 = make_float4(accr[2], acci[2], accr[3], acci[3]);
    *reinterpret_cast<float4*>(st + sidx)     = o0;
    *reinterpret_cast<float4*>(st + sidx + 4) = o1;
}

// ---------------------------------------------------------------------------
// K4: sequential inter-chunk complex scan
// ---------------------------------------------------------------------------
__global__ __launch_bounds__(1024) void k_scan(const float* __restrict__ ctbuf,
                                               const float* __restrict__ st,
                                               const float* __restrict__ init_ssm,
                                               float* __restrict__ Sin)
{
    const int h = blockIdx.x, b = blockIdx.y;
    __shared__ float Tr[NCHUNK], Ti[NCHUNK];
    const int t = threadIdx.x;
    if (t < NCHUNK) {
        const size_t ci2 = (((size_t)b * NHEADS + h) * NCHUNK + t) * 2;
        const float e = expf(ctbuf[ci2]);
        float sn, cn; sincosf(ctbuf[ci2 + 1], &sn, &cn);
        Tr[t] = e * cn; Ti[t] = e * sn;
    }
    __syncthreads();
    const int p = t >> 4, n = t & 15;
    const size_t ii = (((size_t)h * HDIM + p) * DSTATE + n) * 2;
    float Sr = init_ssm[ii], Si = init_ssm[ii + 1];
    for (int z = 0; z < NCHUNK; ++z) {
        const size_t idx = (((((size_t)b * NCHUNK + z) * NHEADS + h) * HDIM + p) * DSTATE + n) * 2;
        Sin[idx] = Sr; Sin[idx + 1] = Si;
        const float sr = st[idx], si = st[idx + 1];
        const float tr = Tr[z], ti = Ti[z];
        const float nr = fmaf(tr, Sr, fmaf(-ti, Si, sr));
        const float ni = fmaf(tr, Si, fmaf(ti, Sr, si));
        Sr = nr; Si = ni;
    }
}

// ---------------------------------------------------------------------------
// K5: Y = G @ xdt + exp(A_cum)*(C . S_in); D residual; gate with clip6(z);
//     write yz as fp16 into A2[M,1024] (GEMM-out A operand)
// ---------------------------------------------------------------------------
__global__ __launch_bounds__(256) void k_yout(const float* __restrict__ conv,
                                              const float* __restrict__ Acum,
                                              const float* __restrict__ Sin,
                                              const float* __restrict__ Dp,
                                              const float* __restrict__ dt_bias,
                                              const float* __restrict__ zx,
                                              _Float16* __restrict__ A2)
{
    const int c = blockIdx.x, h = blockIdx.y, b = blockIdx.z;
    __shared__ float xdt[CHK][HDIM];
    __shared__ float Gr[CHK][CHK + 1];
    __shared__ float Gi[CHK][CHK + 1];
    __shared__ float Bsh[CHK][DSTATE + 1];
    __shared__ float Csh[CHK][DSTATE + 1];
    __shared__ float cumr[CHK], cumi[CHK], Er[CHK], Ei[CHK], dts[CHK];
    const int t = threadIdx.x;

    if (t < 64) {
        const int l = t;
        const int row = b * SEQL + c * CHK + l;
        dts[l] = fminf(expf(zx[(size_t)row * DIP + 1568 + h] + dt_bias[h]), 6.0f);
        const size_t aidx = ((((size_t)b * NHEADS + h) * NCHUNK + c) * CHK + l) * 2;
        const float cr = Acum[aidx], ci = Acum[aidx + 1];
        cumr[l] = cr; cumi[l] = ci;
        const float e = expf(cr);
        float sn, cn; sincosf(ci, &sn, &cn);
        Er[l] = e * cn; Ei[l] = e * sn;
    }
    __syncthreads();

#pragma unroll
    for (int q = 0; q < 4; ++q) {
        const int g = t + q * 256;
        const int l = g >> 4, p4 = (g & 15) * 4;
        const float4 v = *reinterpret_cast<const float4*>(
            conv + (size_t)(b * SEQL + c * CHK + l) * CONVD + h * HDIM + p4);
        const float d = dts[l];
        xdt[l][p4 + 0] = v.x * d; xdt[l][p4 + 1] = v.y * d;
        xdt[l][p4 + 2] = v.z * d; xdt[l][p4 + 3] = v.w * d;
    }
    {
        const int l = t >> 2, n4 = (t & 3) * 4;
        const float* cp = conv + (size_t)(b * SEQL + c * CHK + l) * CONVD;
        const float4 bv = *reinterpret_cast<const float4*>(cp + DINNER + n4);
        const float4 cv = *reinterpret_cast<const float4*>(cp + DINNER + DSTATE + n4);
        Bsh[l][n4 + 0] = bv.x; Bsh[l][n4 + 1] = bv.y; Bsh[l][n4 + 2] = bv.z; Bsh[l][n4 + 3] = bv.w;
        Csh[l][n4 + 0] = cv.x; Csh[l][n4 + 1] = cv.y; Csh[l][n4 + 2] = cv.z; Csh[l][n4 + 3] = cv.w;
    }
    __syncthreads();

#pragma unroll
    for (int q = 0; q < 16; ++q) {
        const int g = t + q * 256;
        const int l = g >> 6, s = g & 63;
        float vr = 0.f, vi = 0.f;
        if (s <= l) {
            float dot = 0.f;
#pragma unroll
            for (int n = 0; n < DSTATE; ++n) dot += Csh[l][n] * Bsh[s][n];
            const float e = expf(cumr[l] - cumr[s]);
            float sn, cn; sincosf(cumi[l] - cumi[s], &sn, &cn);
            vr = dot * e * cn;
            vi = dot * e * sn;
        }
        Gr[l][s] = vr; Gi[l][s] = vi;
    }
    __syncthreads();

    const int tx = t & 15, ty = t >> 4;
    float accr[4][4], acci[4][4];
#pragma unroll
    for (int i = 0; i < 4; ++i)
#pragma unroll
        for (int j = 0; j < 4; ++j) { accr[i][j] = 0.f; acci[i][j] = 0.f; }

    const int send = (((int)(t >> 6)) + 1) * 16;
    for (int s = 0; s < send; ++s) {
        const float4 xq = *reinterpret_cast<const float4*>(&xdt[s][tx * 4]);
        const float xv[4] = {xq.x, xq.y, xq.z, xq.w};
#pragma unroll
        for (int i = 0; i < 4; ++i) {
            const int l = ty * 4 + i;
            const float gr = Gr[l][s], gi = Gi[l][s];
#pragma unroll
            for (int j = 0; j < 4; ++j) {
                accr[i][j] = fmaf(gr, xv[j], accr[i][j]);
                acci[i][j] = fmaf(gi, xv[j], acci[i][j]);
            }
        }
    }

    const float* SinB = Sin + ((((size_t)b * NCHUNK + c) * NHEADS + h) * HDIM) * DSTATE * 2;
    const float dcoef = Dp[2 * h];
#pragma unroll
    for (int j = 0; j < 4; ++j) {
        const int p = tx * 4 + j;
        float sv[32];
        const float4* sp = reinterpret_cast<const float4*>(SinB + (size_t)p * DSTATE * 2);
#pragma unroll
        for (int q = 0; q < 8; ++q) {
            const float4 v4 = sp[q];
            sv[q * 4 + 0] = v4.x; sv[q * 4 + 1] = v4.y; sv[q * 4 + 2] = v4.z; sv[q * 4 + 3] = v4.w;
        }
#pragma unroll
        for (int i = 0; i < 4; ++i) {
            const int l = ty * 4 + i;
            float Or = 0.f, Oi = 0.f;
#pragma unroll
            for (int n = 0; n < DSTATE; ++n) {
                const float cv = Csh[l][n];
                Or = fmaf(cv, sv[2 * n], Or);
                Oi = fmaf(cv, sv[2 * n + 1], Oi);
            }
            const float er = Er[l], ei = Ei[l];
            float yr = accr[i][j] + er * Or - ei * Oi;
            float yi = acci[i][j] + er * Oi + ei * Or;
            const int row = b * SEQL + c * CHK + l;
            const float xinv = conv[(size_t)row * CONVD + h * HDIM + p];
            yr = fmaf(xinv, dcoef, yr);
            const size_t zidx = (size_t)row * DIP + h * 128 + p;
            const float zr = zx[zidx], zi2 = zx[zidx + 64];
            const size_t aidx2 = (size_t)row * DZCOLS + h * 128 + p;
            A2[aidx2]      = (_Float16)(yr * clip6f(zr));
            A2[aidx2 + 64] = (_Float16)(yi * clip6f(zi2));
        }
    }
}

// ---------------------------------------------------------------------------
// K6a: per-row RMS scale over the 1024 yz cols (fp16 A2)
// ---------------------------------------------------------------------------
__global__ __launch_bounds__(256) void k_rms(const _Float16* __restrict__ A2,
                                             float* __restrict__ scale)
{
    const int w = threadIdx.x >> 6, lane = threadIdx.x & 63;
    const int row = blockIdx.x * 4 + w;
    const _Float16* p = A2 + (size_t)row * DZCOLS + lane * 16;
    float ss = 0.f;
#pragma unroll
    for (int q = 0; q < 2; ++q) {
        const half8 h = *reinterpret_cast<const half8*>(p + q * 8);
#pragma unroll
        for (int e = 0; e < 8; ++e) {
            const float v = (float)h[e];
            ss += v * v;
        }
    }
#pragma unroll
    for (int off = 32; off > 0; off >>= 1) ss += __shfl_down(ss, off);
    if (lane == 0) scale[row] = rsqrtf(ss * (1.0f / 1024.0f) + 1e-5f);
}

// ---------------------------------------------------------------------------
extern "C" void kernel_launch(void* const* d_in, const int* in_sizes, int n_in,
                              void* d_out, int out_size, void* d_ws, size_t ws_size,
                              hipStream_t stream)
{
    const float* x         = (const float*)d_in[0];
    const float* W_in      = (const float*)d_in[1];
    const float* conv_w    = (const float*)d_in[2];
    const float* conv_b    = (const float*)d_in[3];
    const float* A_log     = (const float*)d_in[4];
    const float* dt_bias   = (const float*)d_in[5];
    const float* Dp        = (const float*)d_in[6];
    const float* init_conv = (const float*)d_in[7];
    const float* init_ssm  = (const float*)d_in[8];
    const float* norm_w    = (const float*)d_in[9];
    const float* W_out     = (const float*)d_in[10];
    float* out = (float*)d_out;

    float* ws      = (float*)d_ws;
    float* zx      = ws;                                   // 25,821,184 f
    float* convout = zx + (size_t)MROWS * DIP;             //  8,912,896 f
    float* Acum    = convout + (size_t)MROWS * CONVD;      //    262,144 f
    float* ctbuf   = Acum + (size_t)BATCHN * NHEADS * NCHUNK * CHK * 2;
    float* stbuf   = ctbuf + (size_t)BATCHN * NHEADS * NCHUNK * 2;
    float* SinBuf  = stbuf + (size_t)BATCHN * NCHUNK * NHEADS * HDIM * DSTATE * 2;
    float* scaleb  = SinBuf + (size_t)BATCHN * NCHUNK * NHEADS * HDIM * DSTATE * 2;
    float* poolf   = scaleb + MROWS;
    // fp16 pool (A16/Bt16 dead before A2 is written -> A2 overlays them)
    _Float16* A16  = (_Float16*)poolf;                     // M*256 halves
    _Float16* Bt16 = A16 + (size_t)MROWS * DMODEL;         // NPAD*256 halves
    _Float16* A2   = A16;                                  // M*1024 halves (overlay)
    _Float16* Wot  = A16 + (size_t)MROWS * DZCOLS;         // 256*1024 halves
    // total ~208 MB

    k_cvt_x<<<dim3(MROWS * DMODEL / 8 / 256), dim3(256), 0, stream>>>(x, A16);
    k_cvt_win<<<dim3(NPAD), dim3(256), 0, stream>>>(W_in, Bt16);
    k_cvt_wout<<<dim3(DZCOLS), dim3(256), 0, stream>>>(W_out, norm_w, Wot);

    k_gemm16<DMODEL, true, false><<<dim3(NPAD / 128, MROWS / 128), dim3(256), 0, stream>>>(
        A16, Bt16, zx, DIP, DIP, nullptr);

    const int convThreads = MROWS * (CONVD / 4);
    k_conv<<<(convThreads + 255) / 256, dim3(256), 0, stream>>>(zx, conv_w, conv_b, init_conv, convout);

    k_states<<<dim3(NCHUNK, NHEADS, BATCHN), dim3(256), 0, stream>>>(
        zx, convout, A_log, dt_bias, Acum, ctbuf, stbuf);

    k_scan<<<dim3(NHEADS, BATCHN), dim3(1024), 0, stream>>>(ctbuf, stbuf, init_ssm, SinBuf);

    k_yout<<<dim3(NCHUNK, NHEADS, BATCHN), dim3(256), 0, stream>>>(
        convout, Acum, SinBuf, Dp, dt_bias, zx, A2);

    k_rms<<<dim3(MROWS / 4), dim3(256), 0, stream>>>(A2, scaleb);

    k_gemm16<DZCOLS, false, true><<<dim3(DMODEL / 128, MROWS / 128), dim3(256), 0, stream>>>(
        A2, Wot, out, DMODEL, DMODEL, scaleb);
}

// Round 8
// 246.378 us; speedup vs baseline: 2.8139x; 1.4071x over previous
//
#include <hip/hip_runtime.h>
#include <math.h>

#define BATCHN 4
#define SEQL   4096
#define DMODEL 256
#define DIP    1576      // in-proj output cols
#define DINNER 512
#define DZCOLS 1024      // 2*D_INNER
#define CONVD  544
#define NHEADS 8
#define HDIM   64
#define DSTATE 16
#define CHK    64
#define NCHUNK 64
#define MROWS  (BATCHN*SEQL)
#define NPAD   1664      // 13*128, padded N for in-proj GEMM

typedef _Float16 half8 __attribute__((ext_vector_type(8)));
typedef short    s16x8 __attribute__((ext_vector_type(8)));
typedef float    f32x4 __attribute__((ext_vector_type(4)));

__device__ __forceinline__ float clip6f(float x) { return fminf(fmaxf(x, 0.0f), 6.0f); }

// ---------------------------------------------------------------------------
// conversions to fp16
// ---------------------------------------------------------------------------
__global__ __launch_bounds__(256) void k_cvt_x(const float* __restrict__ X,
                                               _Float16* __restrict__ A)
{
    const int gid = blockIdx.x * 256 + threadIdx.x;   // M*256/8 threads
    const float4 a = *reinterpret_cast<const float4*>(X + (size_t)gid * 8);
    const float4 b = *reinterpret_cast<const float4*>(X + (size_t)gid * 8 + 4);
    half8 h;
    h[0] = (_Float16)a.x; h[1] = (_Float16)a.y; h[2] = (_Float16)a.z; h[3] = (_Float16)a.w;
    h[4] = (_Float16)b.x; h[5] = (_Float16)b.y; h[6] = (_Float16)b.z; h[7] = (_Float16)b.w;
    *reinterpret_cast<half8*>(A + (size_t)gid * 8) = h;
}

// W_in[256,1576] -> Bt[1664,256] fp16 (zero pad n>=1576)
__global__ __launch_bounds__(256) void k_cvt_win(const float* __restrict__ W,
                                                 _Float16* __restrict__ Bt)
{
    const int gid = blockIdx.x * 256 + threadIdx.x;   // NPAD*256 threads
    const int k = gid & 255, n = gid >> 8;
    const float v = (n < DIP) ? W[(size_t)k * DIP + n] : 0.0f;
    Bt[gid] = (_Float16)v;
}

// W_out[1024,256]*norm_w[k] -> Wot[256,1024] fp16
__global__ __launch_bounds__(256) void k_cvt_wout(const float* __restrict__ W,
                                                  const float* __restrict__ nw,
                                                  _Float16* __restrict__ Bt)
{
    const int gid = blockIdx.x * 256 + threadIdx.x;   // 256*1024 threads
    const int k = gid & 1023, n = gid >> 10;
    Bt[gid] = (_Float16)(W[(size_t)k * DMODEL + n] * nw[k]);
}

// ---------------------------------------------------------------------------
// fp16 MFMA GEMM: C[M,ldc] (fp32) = A[M,KTOT] @ Bt[N,KTOT]^T
// ---------------------------------------------------------------------------
template<int KTOT, bool NGUARD, bool SCALE>
__global__ __launch_bounds__(256) void k_gemm16(const _Float16* __restrict__ A,
                                                const _Float16* __restrict__ Bt,
                                                float* __restrict__ C,
                                                const int ldc, const int ncols,
                                                const float* __restrict__ scale)
{
    __shared__ _Float16 As[128][72];
    __shared__ _Float16 Bs[128][72];
    const int t  = threadIdx.x;
    const int m0 = blockIdx.y * 128;
    const int n0 = blockIdx.x * 128;
    const int lane = t & 63, wid = t >> 6;
    const int wr = wid >> 1, wc = wid & 1;
    const int fr = lane & 15, fq = lane >> 4;

    f32x4 acc[4][4];
#pragma unroll
    for (int m = 0; m < 4; ++m)
#pragma unroll
        for (int n = 0; n < 4; ++n)
#pragma unroll
            for (int e = 0; e < 4; ++e) acc[m][n][e] = 0.0f;

    for (int kt = 0; kt < KTOT; kt += 64) {
#pragma unroll
        for (int q = 0; q < 4; ++q) {
            const int idx = t + q * 256;
            const int r = idx >> 3, ch = idx & 7;
            *reinterpret_cast<s16x8*>(&As[r][ch * 8]) =
                *reinterpret_cast<const s16x8*>(A + (size_t)(m0 + r) * KTOT + kt + ch * 8);
            *reinterpret_cast<s16x8*>(&Bs[r][ch * 8]) =
                *reinterpret_cast<const s16x8*>(Bt + (size_t)(n0 + r) * KTOT + kt + ch * 8);
        }
        __syncthreads();
#pragma unroll
        for (int ks = 0; ks < 64; ks += 32) {
            half8 af[4], bf[4];
#pragma unroll
            for (int m = 0; m < 4; ++m)
                af[m] = *reinterpret_cast<const half8*>(&As[wr * 64 + m * 16 + fr][ks + fq * 8]);
#pragma unroll
            for (int n = 0; n < 4; ++n)
                bf[n] = *reinterpret_cast<const half8*>(&Bs[wc * 64 + n * 16 + fr][ks + fq * 8]);
#pragma unroll
            for (int m = 0; m < 4; ++m)
#pragma unroll
                for (int n = 0; n < 4; ++n)
                    acc[m][n] = __builtin_amdgcn_mfma_f32_16x16x32_f16(af[m], bf[n], acc[m][n], 0, 0, 0);
        }
        __syncthreads();
    }

#pragma unroll
    for (int m = 0; m < 4; ++m)
#pragma unroll
        for (int j = 0; j < 4; ++j) {
            const int row = m0 + wr * 64 + m * 16 + fq * 4 + j;
            const float sc = SCALE ? scale[row] : 1.0f;
#pragma unroll
            for (int n = 0; n < 4; ++n) {
                const int col = n0 + wc * 64 + n * 16 + fr;
                if (!NGUARD || col < ncols)
                    C[(size_t)row * ldc + col] = acc[m][n][j] * sc;
            }
        }
}

// ---------------------------------------------------------------------------
// K2: causal conv1d (K=4) over xBC cols of zx, relu6, -> convout[M,544]
// ---------------------------------------------------------------------------
__global__ __launch_bounds__(256) void k_conv(const float* __restrict__ zx,
                                              const float* __restrict__ conv_w,
                                              const float* __restrict__ conv_b,
                                              const float* __restrict__ init_conv,
                                              float* __restrict__ convout)
{
    const int NC4 = CONVD / 4; // 136
    int gid = blockIdx.x * 256 + threadIdx.x;
    if (gid >= MROWS * NC4) return;
    const int row  = gid / NC4;
    const int c    = (gid % NC4) * 4;
    const int b    = row / SEQL;
    const int tpos = row % SEQL;
    float4 acc = *reinterpret_cast<const float4*>(conv_b + c);
#pragma unroll
    for (int j = 0; j < 4; ++j) {
        const int srct = tpos - 3 + j;
        float4 v;
        if (srct >= 0)
            v = *reinterpret_cast<const float4*>(zx + (size_t)(b * SEQL + srct) * DIP + DZCOLS + c);
        else
            v = *reinterpret_cast<const float4*>(init_conv + (size_t)(tpos + 1 + j) * CONVD + c);
        const float4 w = *reinterpret_cast<const float4*>(conv_w + (size_t)j * CONVD + c);
        acc.x = fmaf(w.x, v.x, acc.x);
        acc.y = fmaf(w.y, v.y, acc.y);
        acc.z = fmaf(w.z, v.z, acc.z);
        acc.w = fmaf(w.w, v.w, acc.w);
    }
    acc.x = clip6f(acc.x); acc.y = clip6f(acc.y);
    acc.z = clip6f(acc.z); acc.w = clip6f(acc.w);
    *reinterpret_cast<float4*>(convout + (size_t)row * CONVD + c) = acc;
}

// ---------------------------------------------------------------------------
// K3: per (b,h,chunk): A_cum (complex wave scan), chunk totals, local states
// ---------------------------------------------------------------------------
__global__ __launch_bounds__(256) void k_states(const float* __restrict__ zx,
                                                const float* __restrict__ conv,
                                                const float* __restrict__ A_log,
                                                const float* __restrict__ dt_bias,
                                                float* __restrict__ Acum,
                                                float* __restrict__ ctbuf,
                                                float* __restrict__ st)
{
    const int c = blockIdx.x, h = blockIdx.y, b = blockIdx.z;
    __shared__ float wr[CHK], wi[CHK];
    __shared__ float xs[CHK][HDIM];
    __shared__ float Bsh[CHK][DSTATE];
    const int t = threadIdx.x;

#pragma unroll
    for (int q = 0; q < 4; ++q) {
        const int g = t + q * 256;
        const int l = g >> 4, p4 = (g & 15) * 4;
        const float4 v = *reinterpret_cast<const float4*>(
            conv + (size_t)(b * SEQL + c * CHK + l) * CONVD + h * HDIM + p4);
        xs[l][p4 + 0] = v.x; xs[l][p4 + 1] = v.y; xs[l][p4 + 2] = v.z; xs[l][p4 + 3] = v.w;
    }
    {
        const int l = t >> 2, n4 = (t & 3) * 4;
        const float4 v = *reinterpret_cast<const float4*>(
            conv + (size_t)(b * SEQL + c * CHK + l) * CONVD + DINNER + n4);
        Bsh[l][n4 + 0] = v.x; Bsh[l][n4 + 1] = v.y; Bsh[l][n4 + 2] = v.z; Bsh[l][n4 + 3] = v.w;
    }

    if (t < 64) {
        const int l = t;
        const int row = b * SEQL + c * CHK + l;
        const float dtv = fminf(__expf(zx[(size_t)row * DIP + 1568 + h] + dt_bias[h]), 6.0f);
        const float Ar = -__expf(A_log[2 * h]);
        const float Ai = A_log[2 * h + 1];
        float cr = Ar * dtv, ci = Ai * dtv;
#pragma unroll
        for (int off = 1; off < 64; off <<= 1) {
            const float pr = __shfl_up(cr, off);
            const float pi = __shfl_up(ci, off);
            if (l >= off) { cr += pr; ci += pi; }
        }
        const size_t aidx = ((((size_t)b * NHEADS + h) * NCHUNK + c) * CHK + l) * 2;
        Acum[aidx] = cr; Acum[aidx + 1] = ci;
        const float ctr = __shfl(cr, 63), cti = __shfl(ci, 63);
        if (l == 63) {
            const size_t ci2 = (((size_t)b * NHEADS + h) * NCHUNK + c) * 2;
            ctbuf[ci2] = ctr; ctbuf[ci2 + 1] = cti;
        }
        const float e = __expf(ctr - cr);
        float sn, cn; sincosf(cti - ci, &sn, &cn);
        wr[l] = e * cn * dtv;
        wi[l] = e * sn * dtv;
    }
    __syncthreads();

    const int p = t >> 2, n0 = (t & 3) * 4;
    float accr[4] = {0.f, 0.f, 0.f, 0.f};
    float acci[4] = {0.f, 0.f, 0.f, 0.f};
    for (int l = 0; l < CHK; ++l) {
        const float xv = xs[l][p];
        const float xr = xv * wr[l];
        const float xi = xv * wi[l];
#pragma unroll
        for (int j = 0; j < 4; ++j) {
            const float bb = Bsh[l][n0 + j];
            accr[j] = fmaf(bb, xr, accr[j]);
            acci[j] = fmaf(bb, xi, acci[j]);
        }
    }
    const size_t sidx = (((((size_t)b * NCHUNK + c) * NHEADS + h) * HDIM + p) * DSTATE + n0) * 2;
    float4 o0 = make_float4(accr[0], acci[0], accr[1], acci[1]);
    float4 o1 = make_float4(accr[2], acci[2], accr[3], acci[3]);
    *reinterpret_cast<float4*>(st + sidx)     = o0;
    *reinterpret_cast<float4*>(st + sidx + 4) = o1;
}

// ---------------------------------------------------------------------------
// K4: sequential inter-chunk complex scan
// ---------------------------------------------------------------------------
__global__ __launch_bounds__(1024) void k_scan(const float* __restrict__ ctbuf,
                                               const float* __restrict__ st,
                                               const float* __restrict__ init_ssm,
                                               float* __restrict__ Sin)
{
    const int h = blockIdx.x, b = blockIdx.y;
    __shared__ float Tr[NCHUNK], Ti[NCHUNK];
    const int t = threadIdx.x;
    if (t < NCHUNK) {
        const size_t ci2 = (((size_t)b * NHEADS + h) * NCHUNK + t) * 2;
        const float e = __expf(ctbuf[ci2]);
        float sn, cn; sincosf(ctbuf[ci2 + 1], &sn, &cn);
        Tr[t] = e * cn; Ti[t] = e * sn;
    }
    __syncthreads();
    const int p = t >> 4, n = t & 15;
    const size_t ii = (((size_t)h * HDIM + p) * DSTATE + n) * 2;
    float Sr = init_ssm[ii], Si = init_ssm[ii + 1];
    for (int z = 0; z < NCHUNK; ++z) {
        const size_t idx = (((((size_t)b * NCHUNK + z) * NHEADS + h) * HDIM + p) * DSTATE + n) * 2;
        Sin[idx] = Sr; Sin[idx + 1] = Si;
        const float sr = st[idx], si = st[idx + 1];
        const float tr = Tr[z], ti = Ti[z];
        const float nr = fmaf(tr, Sr, fmaf(-ti, Si, sr));
        const float ni = fmaf(tr, Si, fmaf(ti, Sr, si));
        Sr = nr; Si = ni;
    }
}

// ---------------------------------------------------------------------------
// K5 (MFMA): Y = G @ xdt + E*(C @ S^T); D residual; gate clip6(z);
//            yz -> fp16 A2[M,1024]
// CB = C.B^T via MFMA (K=16 padded to 32); G = CB * exp(segsum) built in
// C/D frags (angle-difference identity, no per-pair sincos), stored fp16 to
// LDS; Y_diag = [Gr|Gi] @ XtT via MFMA; Y_off = C @ [Sr|Si]^T via MFMA.
// ---------------------------------------------------------------------------
__global__ __launch_bounds__(256) void k_yout(const float* __restrict__ conv,
                                              const float* __restrict__ Acum,
                                              const float* __restrict__ Sin,
                                              const float* __restrict__ Dp,
                                              const float* __restrict__ dt_bias,
                                              const float* __restrict__ zx,
                                              _Float16* __restrict__ A2)
{
    const int c = blockIdx.x, h = blockIdx.y, b = blockIdx.z;
    __shared__ _Float16 Csh[64][40];   // A-operand (row l, K=n, zero-padded 16..31)
    __shared__ _Float16 Bsh[64][40];   // B-operand (col s, K=n)
    __shared__ _Float16 Srs[64][40];   // B-operand (col p, K=n)
    __shared__ _Float16 Sis[64][40];
    __shared__ _Float16 Xt[64][72];    // B-operand (col p, K=s): x[s][p]*dt[s]
    __shared__ _Float16 Gr[64][72];    // A-operand (row l, K=s)
    __shared__ _Float16 Gi[64][72];
    __shared__ float dts[64], cumr[64], sl_[64], cl_[64], Er[64], Ei[64];
    const int t = threadIdx.x;
    const int lane = t & 63, w = t >> 6;
    const int fr = lane & 15, fq = lane >> 4;
    const int rowb = b * SEQL + c * CHK;

    if (t < 64) {
        const int l = t, row = rowb + l;
        dts[l] = fminf(__expf(zx[(size_t)row * DIP + 1568 + h] + dt_bias[h]), 6.0f);
        const size_t aidx = ((((size_t)b * NHEADS + h) * NCHUNK + c) * CHK + l) * 2;
        const float cr = Acum[aidx], ci = Acum[aidx + 1];
        cumr[l] = cr;
        float sn, cn; sincosf(ci, &sn, &cn);
        sl_[l] = sn; cl_[l] = cn;
        const float e = __expf(cr);
        Er[l] = e * cn; Ei[l] = e * sn;
    }
    {   // B, C, S_in tiles (fp16) + zero pads
        const int l = t >> 2, n0 = (t & 3) * 4;
        const float* cp = conv + (size_t)(rowb + l) * CONVD + DINNER;
        const float4 bv = *reinterpret_cast<const float4*>(cp + n0);
        const float4 cv = *reinterpret_cast<const float4*>(cp + DSTATE + n0);
        Bsh[l][n0 + 0] = (_Float16)bv.x; Bsh[l][n0 + 1] = (_Float16)bv.y;
        Bsh[l][n0 + 2] = (_Float16)bv.z; Bsh[l][n0 + 3] = (_Float16)bv.w;
        Csh[l][n0 + 0] = (_Float16)cv.x; Csh[l][n0 + 1] = (_Float16)cv.y;
        Csh[l][n0 + 2] = (_Float16)cv.z; Csh[l][n0 + 3] = (_Float16)cv.w;
        const float* sp = Sin + ((((size_t)b * NCHUNK + c) * NHEADS + h) * HDIM + l) * (DSTATE * 2) + n0 * 2;
        const float4 s0 = *reinterpret_cast<const float4*>(sp);
        const float4 s1 = *reinterpret_cast<const float4*>(sp + 4);
        Srs[l][n0 + 0] = (_Float16)s0.x; Sis[l][n0 + 0] = (_Float16)s0.y;
        Srs[l][n0 + 1] = (_Float16)s0.z; Sis[l][n0 + 1] = (_Float16)s0.w;
        Srs[l][n0 + 2] = (_Float16)s1.x; Sis[l][n0 + 2] = (_Float16)s1.y;
        Srs[l][n0 + 3] = (_Float16)s1.z; Sis[l][n0 + 3] = (_Float16)s1.w;
        const int z0 = 16 + (t & 3) * 4;
#pragma unroll
        for (int e = 0; e < 4; ++e) {
            Bsh[l][z0 + e] = (_Float16)0.0f;
            Csh[l][z0 + e] = (_Float16)0.0f;
            Srs[l][z0 + e] = (_Float16)0.0f;
            Sis[l][z0 + e] = (_Float16)0.0f;
        }
    }
    __syncthreads();

    // Xt[p][s] = x[s][p]*dt[s]  (needs dts)
#pragma unroll
    for (int q = 0; q < 4; ++q) {
        const int g = t + q * 256;
        const int l = g >> 4, p4 = (g & 15) * 4;
        const float4 v = *reinterpret_cast<const float4*>(
            conv + (size_t)(rowb + l) * CONVD + h * HDIM + p4);
        const float d = dts[l];
        Xt[p4 + 0][l] = (_Float16)(v.x * d);
        Xt[p4 + 1][l] = (_Float16)(v.y * d);
        Xt[p4 + 2][l] = (_Float16)(v.z * d);
        Xt[p4 + 3][l] = (_Float16)(v.w * d);
    }

    // CB = C.B^T  (wave w owns rows [w*16, w*16+16))
    const half8 afC = *reinterpret_cast<const half8*>(&Csh[w * 16 + fr][fq * 8]);
    f32x4 cb[4];
#pragma unroll
    for (int nf = 0; nf < 4; ++nf) {
        const half8 bfB = *reinterpret_cast<const half8*>(&Bsh[nf * 16 + fr][fq * 8]);
        f32x4 z = {0.f, 0.f, 0.f, 0.f};
        cb[nf] = __builtin_amdgcn_mfma_f32_16x16x32_f16(afC, bfB, z, 0, 0, 0);
    }
    // G = CB * exp(segsum)  (mask s<=l), store fp16
#pragma unroll
    for (int nf = 0; nf < 4; ++nf) {
        const int s = nf * 16 + fr;
        const float crs = cumr[s], sls = sl_[s], cls = cl_[s];
#pragma unroll
        for (int j = 0; j < 4; ++j) {
            const int l = w * 16 + fq * 4 + j;
            const float dr = fminf(cumr[l] - crs, 0.0f);
            const float e = __expf(dr);
            const float cd = cl_[l] * cls + sl_[l] * sls;
            const float sd = sl_[l] * cls - cl_[l] * sls;
            const float ge = (s <= l) ? cb[nf][j] * e : 0.0f;
            Gr[l][s] = (_Float16)(ge * cd);
            Gi[l][s] = (_Float16)(ge * sd);
        }
    }
    __syncthreads();

    // Y_diag = G @ xdt
    f32x4 accr[4], acci[4];
#pragma unroll
    for (int nf = 0; nf < 4; ++nf)
#pragma unroll
        for (int e = 0; e < 4; ++e) { accr[nf][e] = 0.f; acci[nf][e] = 0.f; }
#pragma unroll
    for (int ks = 0; ks < 64; ks += 32) {
        const half8 ar = *reinterpret_cast<const half8*>(&Gr[w * 16 + fr][ks + fq * 8]);
        const half8 ai = *reinterpret_cast<const half8*>(&Gi[w * 16 + fr][ks + fq * 8]);
#pragma unroll
        for (int nf = 0; nf < 4; ++nf) {
            const half8 bx = *reinterpret_cast<const half8*>(&Xt[nf * 16 + fr][ks + fq * 8]);
            accr[nf] = __builtin_amdgcn_mfma_f32_16x16x32_f16(ar, bx, accr[nf], 0, 0, 0);
            acci[nf] = __builtin_amdgcn_mfma_f32_16x16x32_f16(ai, bx, acci[nf], 0, 0, 0);
        }
    }
    // Y_off inner: O = C @ S^T
    f32x4 orr[4], oii[4];
#pragma unroll
    for (int nf = 0; nf < 4; ++nf) {
        const half8 br = *reinterpret_cast<const half8*>(&Srs[nf * 16 + fr][fq * 8]);
        const half8 bi = *reinterpret_cast<const half8*>(&Sis[nf * 16 + fr][fq * 8]);
        f32x4 z = {0.f, 0.f, 0.f, 0.f};
        orr[nf] = __builtin_amdgcn_mfma_f32_16x16x32_f16(afC, br, z, 0, 0, 0);
        oii[nf] = __builtin_amdgcn_mfma_f32_16x16x32_f16(afC, bi, z, 0, 0, 0);
    }

    // epilogue: Y = Ydiag + E*O; D residual; z-gate; fp16 store
    const float dcoef = Dp[2 * h];
#pragma unroll
    for (int nf = 0; nf < 4; ++nf) {
        const int p = nf * 16 + fr;
#pragma unroll
        for (int j = 0; j < 4; ++j) {
            const int l = w * 16 + fq * 4 + j;
            const int row = rowb + l;
            const float er = Er[l], ei = Ei[l];
            float yr = accr[nf][j] + er * orr[nf][j] - ei * oii[nf][j];
            float yi = acci[nf][j] + er * oii[nf][j] + ei * orr[nf][j];
            const float xinv = conv[(size_t)row * CONVD + h * HDIM + p];
            yr = fmaf(xinv, dcoef, yr);
            const size_t zidx = (size_t)row * DIP + h * 128 + p;
            const size_t aidx2 = (size_t)row * DZCOLS + h * 128 + p;
            A2[aidx2]      = (_Float16)(yr * clip6f(zx[zidx]));
            A2[aidx2 + 64] = (_Float16)(yi * clip6f(zx[zidx + 64]));
        }
    }
}

// ---------------------------------------------------------------------------
// K6a: per-row RMS scale over the 1024 yz cols (fp16 A2)
// ---------------------------------------------------------------------------
__global__ __launch_bounds__(256) void k_rms(const _Float16* __restrict__ A2,
                                             float* __restrict__ scale)
{
    const int w = threadIdx.x >> 6, lane = threadIdx.x & 63;
    const int row = blockIdx.x * 4 + w;
    const _Float16* p = A2 + (size_t)row * DZCOLS + lane * 16;
    float ss = 0.f;
#pragma unroll
    for (int q = 0; q < 2; ++q) {
        const half8 h = *reinterpret_cast<const half8*>(p + q * 8);
#pragma unroll
        for (int e = 0; e < 8; ++e) {
            const float v = (float)h[e];
            ss += v * v;
        }
    }
#pragma unroll
    for (int off = 32; off > 0; off >>= 1) ss += __shfl_down(ss, off);
    if (lane == 0) scale[row] = rsqrtf(ss * (1.0f / 1024.0f) + 1e-5f);
}

// ---------------------------------------------------------------------------
extern "C" void kernel_launch(void* const* d_in, const int* in_sizes, int n_in,
                              void* d_out, int out_size, void* d_ws, size_t ws_size,
                              hipStream_t stream)
{
    const float* x         = (const float*)d_in[0];
    const float* W_in      = (const float*)d_in[1];
    const float* conv_w    = (const float*)d_in[2];
    const float* conv_b    = (const float*)d_in[3];
    const float* A_log     = (const float*)d_in[4];
    const float* dt_bias   = (const float*)d_in[5];
    const float* Dp        = (const float*)d_in[6];
    const float* init_conv = (const float*)d_in[7];
    const float* init_ssm  = (const float*)d_in[8];
    const float* norm_w    = (const float*)d_in[9];
    const float* W_out     = (const float*)d_in[10];
    float* out = (float*)d_out;

    float* ws      = (float*)d_ws;
    float* zx      = ws;                                   // 25,821,184 f
    float* convout = zx + (size_t)MROWS * DIP;             //  8,912,896 f
    float* Acum    = convout + (size_t)MROWS * CONVD;      //    262,144 f
    float* ctbuf   = Acum + (size_t)BATCHN * NHEADS * NCHUNK * CHK * 2;
    float* stbuf   = ctbuf + (size_t)BATCHN * NHEADS * NCHUNK * 2;
    float* SinBuf  = stbuf + (size_t)BATCHN * NCHUNK * NHEADS * HDIM * DSTATE * 2;
    float* scaleb  = SinBuf + (size_t)BATCHN * NCHUNK * NHEADS * HDIM * DSTATE * 2;
    float* poolf   = scaleb + MROWS;
    _Float16* A16  = (_Float16*)poolf;                     // M*256 halves
    _Float16* Bt16 = A16 + (size_t)MROWS * DMODEL;         // NPAD*256 halves
    _Float16* A2   = A16;                                  // M*1024 halves (overlay)
    _Float16* Wot  = A16 + (size_t)MROWS * DZCOLS;         // 256*1024 halves

    k_cvt_x<<<dim3(MROWS * DMODEL / 8 / 256), dim3(256), 0, stream>>>(x, A16);
    k_cvt_win<<<dim3(NPAD), dim3(256), 0, stream>>>(W_in, Bt16);
    k_cvt_wout<<<dim3(DZCOLS), dim3(256), 0, stream>>>(W_out, norm_w, Wot);

    k_gemm16<DMODEL, true, false><<<dim3(NPAD / 128, MROWS / 128), dim3(256), 0, stream>>>(
        A16, Bt16, zx, DIP, DIP, nullptr);

    const int convThreads = MROWS * (CONVD / 4);
    k_conv<<<(convThreads + 255) / 256, dim3(256), 0, stream>>>(zx, conv_w, conv_b, init_conv, convout);

    k_states<<<dim3(NCHUNK, NHEADS, BATCHN), dim3(256), 0, stream>>>(
        zx, convout, A_log, dt_bias, Acum, ctbuf, stbuf);

    k_scan<<<dim3(NHEADS, BATCHN), dim3(1024), 0, stream>>>(ctbuf, stbuf, init_ssm, SinBuf);

    k_yout<<<dim3(NCHUNK, NHEADS, BATCHN), dim3(256), 0, stream>>>(
        convout, Acum, SinBuf, Dp, dt_bias, zx, A2);

    k_rms<<<dim3(MROWS / 4), dim3(256), 0, stream>>>(A2, scaleb);

    k_gemm16<DZCOLS, false, true><<<dim3(DMODEL / 128, MROWS / 128), dim3(256), 0, stream>>>(
        A2, Wot, out, DMODEL, DMODEL, scaleb);
}

// Round 9
// 235.643 us; speedup vs baseline: 2.9420x; 1.0456x over previous
//
#include <hip/hip_runtime.h>
#include <math.h>

#define BATCHN 4
#define SEQL   4096
#define DMODEL 256
#define DIP    1576      // in-proj output cols
#define DINNER 512
#define DZCOLS 1024      // 2*D_INNER
#define CONVD  544
#define NHEADS 8
#define HDIM   64
#define DSTATE 16
#define CHK    64
#define NCHUNK 64
#define MROWS  (BATCHN*SEQL)
#define NPAD   1664      // 13*128, padded N for in-proj GEMM

typedef _Float16 half8 __attribute__((ext_vector_type(8)));
typedef _Float16 half4 __attribute__((ext_vector_type(4)));
typedef short    s16x8 __attribute__((ext_vector_type(8)));
typedef float    f32x4 __attribute__((ext_vector_type(4)));

__device__ __forceinline__ float clip6f(float x) { return fminf(fmaxf(x, 0.0f), 6.0f); }

// ---------------------------------------------------------------------------
// W_in[256,1576] -> Bt[1664,256] fp16 (zero pad n>=1576)
// ---------------------------------------------------------------------------
__global__ __launch_bounds__(256) void k_cvt_win(const float* __restrict__ W,
                                                 _Float16* __restrict__ Bt)
{
    const int gid = blockIdx.x * 256 + threadIdx.x;   // NPAD*256 threads
    const int k = gid & 255, n = gid >> 8;
    const float v = (n < DIP) ? W[(size_t)k * DIP + n] : 0.0f;
    Bt[gid] = (_Float16)v;
}

// W_out[1024,256]*norm_w[k] -> Wot[256,1024] fp16
__global__ __launch_bounds__(256) void k_cvt_wout(const float* __restrict__ W,
                                                  const float* __restrict__ nw,
                                                  _Float16* __restrict__ Bt)
{
    const int gid = blockIdx.x * 256 + threadIdx.x;   // 256*1024 threads
    const int k = gid & 1023, n = gid >> 10;
    Bt[gid] = (_Float16)(W[(size_t)k * DMODEL + n] * nw[k]);
}

// ---------------------------------------------------------------------------
// K1: zx16[M,1576](fp16) = x[M,256](fp32) @ W_in; dt_raw cols -> fp32 dtraw
//     (fp32 A staged+converted in-register; no separate cvt_x kernel)
// ---------------------------------------------------------------------------
__global__ __launch_bounds__(256) void k_gemm_in(const float* __restrict__ X,
                                                 const _Float16* __restrict__ Bt,
                                                 _Float16* __restrict__ zx,
                                                 float* __restrict__ dtraw)
{
    __shared__ _Float16 As[128][72];
    __shared__ _Float16 Bs[128][72];
    const int t  = threadIdx.x;
    const int m0 = blockIdx.y * 128;
    const int n0 = blockIdx.x * 128;
    const int lane = t & 63, wid = t >> 6;
    const int wr = wid >> 1, wc = wid & 1;
    const int fr = lane & 15, fq = lane >> 4;

    f32x4 acc[4][4];
#pragma unroll
    for (int m = 0; m < 4; ++m)
#pragma unroll
        for (int n = 0; n < 4; ++n)
#pragma unroll
            for (int e = 0; e < 4; ++e) acc[m][n][e] = 0.0f;

    for (int kt = 0; kt < DMODEL; kt += 64) {
#pragma unroll
        for (int q = 0; q < 4; ++q) {
            const int idx = t + q * 256;
            const int r = idx >> 3, ch = idx & 7;
            const float* xp = X + (size_t)(m0 + r) * DMODEL + kt + ch * 8;
            const float4 a0 = *reinterpret_cast<const float4*>(xp);
            const float4 a1 = *reinterpret_cast<const float4*>(xp + 4);
            half8 hv;
            hv[0] = (_Float16)a0.x; hv[1] = (_Float16)a0.y;
            hv[2] = (_Float16)a0.z; hv[3] = (_Float16)a0.w;
            hv[4] = (_Float16)a1.x; hv[5] = (_Float16)a1.y;
            hv[6] = (_Float16)a1.z; hv[7] = (_Float16)a1.w;
            *reinterpret_cast<half8*>(&As[r][ch * 8]) = hv;
            *reinterpret_cast<s16x8*>(&Bs[r][ch * 8]) =
                *reinterpret_cast<const s16x8*>(Bt + (size_t)(n0 + r) * DMODEL + kt + ch * 8);
        }
        __syncthreads();
#pragma unroll
        for (int ks = 0; ks < 64; ks += 32) {
            half8 af[4], bf[4];
#pragma unroll
            for (int m = 0; m < 4; ++m)
                af[m] = *reinterpret_cast<const half8*>(&As[wr * 64 + m * 16 + fr][ks + fq * 8]);
#pragma unroll
            for (int n = 0; n < 4; ++n)
                bf[n] = *reinterpret_cast<const half8*>(&Bs[wc * 64 + n * 16 + fr][ks + fq * 8]);
#pragma unroll
            for (int m = 0; m < 4; ++m)
#pragma unroll
                for (int n = 0; n < 4; ++n)
                    acc[m][n] = __builtin_amdgcn_mfma_f32_16x16x32_f16(af[m], bf[n], acc[m][n], 0, 0, 0);
        }
        __syncthreads();
    }

#pragma unroll
    for (int m = 0; m < 4; ++m)
#pragma unroll
        for (int j = 0; j < 4; ++j) {
            const int row = m0 + wr * 64 + m * 16 + fq * 4 + j;
#pragma unroll
            for (int n = 0; n < 4; ++n) {
                const int col = n0 + wc * 64 + n * 16 + fr;
                const float v = acc[m][n][j];
                if (col < DIP) {
                    zx[(size_t)row * DIP + col] = (_Float16)v;
                    if (col >= 3 * DINNER + 2 * DSTATE)        // 1568..1575: dt_raw fp32
                        dtraw[(size_t)row * 8 + (col - (3 * DINNER + 2 * DSTATE))] = v;
                }
            }
        }
}

// ---------------------------------------------------------------------------
// K2: causal conv1d (K=4) over xBC cols of zx16, relu6 -> convout16[M,544]
// ---------------------------------------------------------------------------
__global__ __launch_bounds__(256) void k_conv(const _Float16* __restrict__ zx,
                                              const float* __restrict__ conv_w,
                                              const float* __restrict__ conv_b,
                                              const float* __restrict__ init_conv,
                                              _Float16* __restrict__ convout)
{
    const int NC8 = CONVD / 8; // 68
    const int gid = blockIdx.x * 256 + threadIdx.x;
    if (gid >= MROWS * NC8) return;
    const int row  = gid / NC8;
    const int c    = (gid % NC8) * 8;
    const int b    = row / SEQL;
    const int tpos = row % SEQL;
    float acc[8];
    {
        const float4 b0 = *reinterpret_cast<const float4*>(conv_b + c);
        const float4 b1 = *reinterpret_cast<const float4*>(conv_b + c + 4);
        acc[0] = b0.x; acc[1] = b0.y; acc[2] = b0.z; acc[3] = b0.w;
        acc[4] = b1.x; acc[5] = b1.y; acc[6] = b1.z; acc[7] = b1.w;
    }
#pragma unroll
    for (int j = 0; j < 4; ++j) {
        const int srct = tpos - 3 + j;
        float v[8];
        if (srct >= 0) {
            const half8 hv = *reinterpret_cast<const half8*>(
                zx + (size_t)(b * SEQL + srct) * DIP + DZCOLS + c);
#pragma unroll
            for (int e = 0; e < 8; ++e) v[e] = (float)hv[e];
        } else {
            const float* ip = init_conv + (size_t)(tpos + 1 + j) * CONVD + c;
            const float4 i0 = *reinterpret_cast<const float4*>(ip);
            const float4 i1 = *reinterpret_cast<const float4*>(ip + 4);
            v[0] = i0.x; v[1] = i0.y; v[2] = i0.z; v[3] = i0.w;
            v[4] = i1.x; v[5] = i1.y; v[6] = i1.z; v[7] = i1.w;
        }
        const float* wp = conv_w + (size_t)j * CONVD + c;
        const float4 w0 = *reinterpret_cast<const float4*>(wp);
        const float4 w1 = *reinterpret_cast<const float4*>(wp + 4);
        const float w[8] = {w0.x, w0.y, w0.z, w0.w, w1.x, w1.y, w1.z, w1.w};
#pragma unroll
        for (int e = 0; e < 8; ++e) acc[e] = fmaf(w[e], v[e], acc[e]);
    }
    half8 hv;
#pragma unroll
    for (int e = 0; e < 8; ++e) hv[e] = (_Float16)clip6f(acc[e]);
    *reinterpret_cast<half8*>(convout + (size_t)row * CONVD + c) = hv;
}

// ---------------------------------------------------------------------------
// K3: per (b,h,chunk): A_cum (complex wave scan), chunk totals, local states
// ---------------------------------------------------------------------------
__global__ __launch_bounds__(256) void k_states(const float* __restrict__ dtraw,
                                                const _Float16* __restrict__ conv,
                                                const float* __restrict__ A_log,
                                                const float* __restrict__ dt_bias,
                                                float* __restrict__ Acum,
                                                float* __restrict__ ctbuf,
                                                float* __restrict__ st)
{
    const int c = blockIdx.x, h = blockIdx.y, b = blockIdx.z;
    __shared__ float wr[CHK], wi[CHK];
    __shared__ float xs[CHK][HDIM];
    __shared__ float Bsh[CHK][DSTATE];
    const int t = threadIdx.x;

#pragma unroll
    for (int q = 0; q < 2; ++q) {
        const int g = t + q * 256;
        const int l = g >> 3, p8 = (g & 7) * 8;
        const half8 hv = *reinterpret_cast<const half8*>(
            conv + (size_t)(b * SEQL + c * CHK + l) * CONVD + h * HDIM + p8);
#pragma unroll
        for (int e = 0; e < 8; ++e) xs[l][p8 + e] = (float)hv[e];
    }
    if (t < 128) {
        const int l = t >> 1, n8 = (t & 1) * 8;
        const half8 hv = *reinterpret_cast<const half8*>(
            conv + (size_t)(b * SEQL + c * CHK + l) * CONVD + DINNER + n8);
#pragma unroll
        for (int e = 0; e < 8; ++e) Bsh[l][n8 + e] = (float)hv[e];
    }

    if (t < 64) {
        const int l = t;
        const int row = b * SEQL + c * CHK + l;
        const float dtv = fminf(__expf(dtraw[(size_t)row * 8 + h] + dt_bias[h]), 6.0f);
        const float Ar = -__expf(A_log[2 * h]);
        const float Ai = A_log[2 * h + 1];
        float cr = Ar * dtv, ci = Ai * dtv;
#pragma unroll
        for (int off = 1; off < 64; off <<= 1) {
            const float pr = __shfl_up(cr, off);
            const float pi = __shfl_up(ci, off);
            if (l >= off) { cr += pr; ci += pi; }
        }
        const size_t aidx = ((((size_t)b * NHEADS + h) * NCHUNK + c) * CHK + l) * 2;
        Acum[aidx] = cr; Acum[aidx + 1] = ci;
        const float ctr = __shfl(cr, 63), cti = __shfl(ci, 63);
        if (l == 63) {
            const size_t ci2 = (((size_t)b * NHEADS + h) * NCHUNK + c) * 2;
            ctbuf[ci2] = ctr; ctbuf[ci2 + 1] = cti;
        }
        const float e = __expf(ctr - cr);
        float sn, cn; sincosf(cti - ci, &sn, &cn);
        wr[l] = e * cn * dtv;
        wi[l] = e * sn * dtv;
    }
    __syncthreads();

    const int p = t >> 2, n0 = (t & 3) * 4;
    float accr[4] = {0.f, 0.f, 0.f, 0.f};
    float acci[4] = {0.f, 0.f, 0.f, 0.f};
    for (int l = 0; l < CHK; ++l) {
        const float xv = xs[l][p];
        const float xr = xv * wr[l];
        const float xi = xv * wi[l];
#pragma unroll
        for (int j = 0; j < 4; ++j) {
            const float bb = Bsh[l][n0 + j];
            accr[j] = fmaf(bb, xr, accr[j]);
            acci[j] = fmaf(bb, xi, acci[j]);
        }
    }
    const size_t sidx = (((((size_t)b * NCHUNK + c) * NHEADS + h) * HDIM + p) * DSTATE + n0) * 2;
    float4 o0 = make_float4(accr[0], acci[0], accr[1], acci[1]);
    float4 o1 = make_float4(accr[2], acci[2], accr[3], acci[3]);
    *reinterpret_cast<float4*>(st + sidx)     = o0;
    *reinterpret_cast<float4*>(st + sidx + 4) = o1;
}

// ---------------------------------------------------------------------------
// K4: sequential inter-chunk complex scan
// ---------------------------------------------------------------------------
__global__ __launch_bounds__(1024) void k_scan(const float* __restrict__ ctbuf,
                                               const float* __restrict__ st,
                                               const float* __restrict__ init_ssm,
                                               float* __restrict__ Sin)
{
    const int h = blockIdx.x, b = blockIdx.y;
    __shared__ float Tr[NCHUNK], Ti[NCHUNK];
    const int t = threadIdx.x;
    if (t < NCHUNK) {
        const size_t ci2 = (((size_t)b * NHEADS + h) * NCHUNK + t) * 2;
        const float e = __expf(ctbuf[ci2]);
        float sn, cn; sincosf(ctbuf[ci2 + 1], &sn, &cn);
        Tr[t] = e * cn; Ti[t] = e * sn;
    }
    __syncthreads();
    const int p = t >> 4, n = t & 15;
    const size_t ii = (((size_t)h * HDIM + p) * DSTATE + n) * 2;
    float Sr = init_ssm[ii], Si = init_ssm[ii + 1];
    for (int z = 0; z < NCHUNK; ++z) {
        const size_t idx = (((((size_t)b * NCHUNK + z) * NHEADS + h) * HDIM + p) * DSTATE + n) * 2;
        Sin[idx] = Sr; Sin[idx + 1] = Si;
        const float sr = st[idx], si = st[idx + 1];
        const float tr = Tr[z], ti = Ti[z];
        const float nr = fmaf(tr, Sr, fmaf(-ti, Si, sr));
        const float ni = fmaf(tr, Si, fmaf(ti, Sr, si));
        Sr = nr; Si = ni;
    }
}

// ---------------------------------------------------------------------------
// K5 (MFMA): Y = G @ xdt + E*(C @ S^T); D residual; gate clip6(z);
//            yz -> fp16 A2[M,1024]; conv/zx inputs now fp16
// ---------------------------------------------------------------------------
__global__ __launch_bounds__(256) void k_yout(const _Float16* __restrict__ conv,
                                              const float* __restrict__ Acum,
                                              const float* __restrict__ Sin,
                                              const float* __restrict__ Dp,
                                              const float* __restrict__ dt_bias,
                                              const float* __restrict__ dtraw,
                                              const _Float16* __restrict__ zx,
                                              _Float16* __restrict__ A2)
{
    const int c = blockIdx.x, h = blockIdx.y, b = blockIdx.z;
    __shared__ _Float16 Csh[64][40];   // A-operand (row l, K=n, zero-padded 16..31)
    __shared__ _Float16 Bsh[64][40];   // B-operand (col s, K=n)
    __shared__ _Float16 Srs[64][40];   // B-operand (col p, K=n)
    __shared__ _Float16 Sis[64][40];
    __shared__ _Float16 Xt[64][72];    // B-operand (col p, K=s): x[s][p]*dt[s]
    __shared__ _Float16 Gr[64][72];    // A-operand (row l, K=s)
    __shared__ _Float16 Gi[64][72];
    __shared__ float dts[64], cumr[64], sl_[64], cl_[64], Er[64], Ei[64];
    const int t = threadIdx.x;
    const int lane = t & 63, w = t >> 6;
    const int fr = lane & 15, fq = lane >> 4;
    const int rowb = b * SEQL + c * CHK;

    if (t < 64) {
        const int l = t, row = rowb + l;
        dts[l] = fminf(__expf(dtraw[(size_t)row * 8 + h] + dt_bias[h]), 6.0f);
        const size_t aidx = ((((size_t)b * NHEADS + h) * NCHUNK + c) * CHK + l) * 2;
        const float cr = Acum[aidx], ci = Acum[aidx + 1];
        cumr[l] = cr;
        float sn, cn; sincosf(ci, &sn, &cn);
        sl_[l] = sn; cl_[l] = cn;
        const float e = __expf(cr);
        Er[l] = e * cn; Ei[l] = e * sn;
    }
    {   // B, C (fp16 direct), S_in (fp32->fp16) tiles + zero pads
        const int l = t >> 2, n4 = (t & 3) * 4;
        const _Float16* cp = conv + (size_t)(rowb + l) * CONVD + DINNER;
        const half4 bv = *reinterpret_cast<const half4*>(cp + n4);
        const half4 cv = *reinterpret_cast<const half4*>(cp + DSTATE + n4);
        Bsh[l][n4 + 0] = bv[0]; Bsh[l][n4 + 1] = bv[1];
        Bsh[l][n4 + 2] = bv[2]; Bsh[l][n4 + 3] = bv[3];
        Csh[l][n4 + 0] = cv[0]; Csh[l][n4 + 1] = cv[1];
        Csh[l][n4 + 2] = cv[2]; Csh[l][n4 + 3] = cv[3];
        const float* sp = Sin + ((((size_t)b * NCHUNK + c) * NHEADS + h) * HDIM + l) * (DSTATE * 2) + n4 * 2;
        const float4 s0 = *reinterpret_cast<const float4*>(sp);
        const float4 s1 = *reinterpret_cast<const float4*>(sp + 4);
        Srs[l][n4 + 0] = (_Float16)s0.x; Sis[l][n4 + 0] = (_Float16)s0.y;
        Srs[l][n4 + 1] = (_Float16)s0.z; Sis[l][n4 + 1] = (_Float16)s0.w;
        Srs[l][n4 + 2] = (_Float16)s1.x; Sis[l][n4 + 2] = (_Float16)s1.y;
        Srs[l][n4 + 3] = (_Float16)s1.z; Sis[l][n4 + 3] = (_Float16)s1.w;
        const int z0 = 16 + (t & 3) * 4;
#pragma unroll
        for (int e = 0; e < 4; ++e) {
            Bsh[l][z0 + e] = (_Float16)0.0f;
            Csh[l][z0 + e] = (_Float16)0.0f;
            Srs[l][z0 + e] = (_Float16)0.0f;
            Sis[l][z0 + e] = (_Float16)0.0f;
        }
    }
    __syncthreads();

    // Xt[p][s] = x[s][p]*dt[s]  (fp16 source)
#pragma unroll
    for (int q = 0; q < 2; ++q) {
        const int g = t + q * 256;
        const int l = g >> 3, p8 = (g & 7) * 8;
        const half8 hv = *reinterpret_cast<const half8*>(
            conv + (size_t)(rowb + l) * CONVD + h * HDIM + p8);
        const float d = dts[l];
#pragma unroll
        for (int e = 0; e < 8; ++e)
            Xt[p8 + e][l] = (_Float16)((float)hv[e] * d);
    }

    // CB = C.B^T  (wave w owns rows [w*16, w*16+16))
    const half8 afC = *reinterpret_cast<const half8*>(&Csh[w * 16 + fr][fq * 8]);
    f32x4 cb[4];
#pragma unroll
    for (int nf = 0; nf < 4; ++nf) {
        const half8 bfB = *reinterpret_cast<const half8*>(&Bsh[nf * 16 + fr][fq * 8]);
        f32x4 z = {0.f, 0.f, 0.f, 0.f};
        cb[nf] = __builtin_amdgcn_mfma_f32_16x16x32_f16(afC, bfB, z, 0, 0, 0);
    }
    // G = CB * exp(segsum)  (mask s<=l), store fp16
#pragma unroll
    for (int nf = 0; nf < 4; ++nf) {
        const int s = nf * 16 + fr;
        const float crs = cumr[s], sls = sl_[s], cls = cl_[s];
#pragma unroll
        for (int j = 0; j < 4; ++j) {
            const int l = w * 16 + fq * 4 + j;
            const float dr = fminf(cumr[l] - crs, 0.0f);
            const float e = __expf(dr);
            const float cd = cl_[l] * cls + sl_[l] * sls;
            const float sd = sl_[l] * cls - cl_[l] * sls;
            const float ge = (s <= l) ? cb[nf][j] * e : 0.0f;
            Gr[l][s] = (_Float16)(ge * cd);
            Gi[l][s] = (_Float16)(ge * sd);
        }
    }
    __syncthreads();

    // Y_diag = G @ xdt
    f32x4 accr[4], acci[4];
#pragma unroll
    for (int nf = 0; nf < 4; ++nf)
#pragma unroll
        for (int e = 0; e < 4; ++e) { accr[nf][e] = 0.f; acci[nf][e] = 0.f; }
#pragma unroll
    for (int ks = 0; ks < 64; ks += 32) {
        const half8 ar = *reinterpret_cast<const half8*>(&Gr[w * 16 + fr][ks + fq * 8]);
        const half8 ai = *reinterpret_cast<const half8*>(&Gi[w * 16 + fr][ks + fq * 8]);
#pragma unroll
        for (int nf = 0; nf < 4; ++nf) {
            const half8 bx = *reinterpret_cast<const half8*>(&Xt[nf * 16 + fr][ks + fq * 8]);
            accr[nf] = __builtin_amdgcn_mfma_f32_16x16x32_f16(ar, bx, accr[nf], 0, 0, 0);
            acci[nf] = __builtin_amdgcn_mfma_f32_16x16x32_f16(ai, bx, acci[nf], 0, 0, 0);
        }
    }
    // Y_off inner: O = C @ S^T
    f32x4 orr[4], oii[4];
#pragma unroll
    for (int nf = 0; nf < 4; ++nf) {
        const half8 br = *reinterpret_cast<const half8*>(&Srs[nf * 16 + fr][fq * 8]);
        const half8 bi = *reinterpret_cast<const half8*>(&Sis[nf * 16 + fr][fq * 8]);
        f32x4 z = {0.f, 0.f, 0.f, 0.f};
        orr[nf] = __builtin_amdgcn_mfma_f32_16x16x32_f16(afC, br, z, 0, 0, 0);
        oii[nf] = __builtin_amdgcn_mfma_f32_16x16x32_f16(afC, bi, z, 0, 0, 0);
    }

    // epilogue: Y = Ydiag + E*O; D residual; z-gate; fp16 store
    const float dcoef = Dp[2 * h];
#pragma unroll
    for (int nf = 0; nf < 4; ++nf) {
        const int p = nf * 16 + fr;
#pragma unroll
        for (int j = 0; j < 4; ++j) {
            const int l = w * 16 + fq * 4 + j;
            const int row = rowb + l;
            const float er = Er[l], ei = Ei[l];
            float yr = accr[nf][j] + er * orr[nf][j] - ei * oii[nf][j];
            float yi = acci[nf][j] + er * oii[nf][j] + ei * orr[nf][j];
            const float xinv = (float)conv[(size_t)row * CONVD + h * HDIM + p];
            yr = fmaf(xinv, dcoef, yr);
            const size_t zidx = (size_t)row * DIP + h * 128 + p;
            const float zr = (float)zx[zidx], zi2 = (float)zx[zidx + 64];
            const size_t aidx2 = (size_t)row * DZCOLS + h * 128 + p;
            A2[aidx2]      = (_Float16)(yr * clip6f(zr));
            A2[aidx2 + 64] = (_Float16)(yi * clip6f(zi2));
        }
    }
}

// ---------------------------------------------------------------------------
// K6: out[M,256](fp32) = (A2 * rms_scale_row) @ Wot^T, RMS fused in-kernel
// ---------------------------------------------------------------------------
__global__ __launch_bounds__(256) void k_gemm_out(const _Float16* __restrict__ A,
                                                  const _Float16* __restrict__ Bt,
                                                  float* __restrict__ C)
{
    __shared__ _Float16 As[128][72];
    __shared__ _Float16 Bs[128][72];
    __shared__ float ssp[128][8];
    __shared__ float scl[128];
    const int t  = threadIdx.x;
    const int m0 = blockIdx.y * 128;
    const int n0 = blockIdx.x * 128;
    const int lane = t & 63, wid = t >> 6;
    const int wr = wid >> 1, wc = wid & 1;
    const int fr = lane & 15, fq = lane >> 4;

    f32x4 acc[4][4];
#pragma unroll
    for (int m = 0; m < 4; ++m)
#pragma unroll
        for (int n = 0; n < 4; ++n)
#pragma unroll
            for (int e = 0; e < 4; ++e) acc[m][n][e] = 0.0f;
    float ss[4] = {0.f, 0.f, 0.f, 0.f};

    for (int kt = 0; kt < DZCOLS; kt += 64) {
#pragma unroll
        for (int q = 0; q < 4; ++q) {
            const int idx = t + q * 256;
            const int r = idx >> 3, ch = idx & 7;
            const half8 av = *reinterpret_cast<const half8*>(
                A + (size_t)(m0 + r) * DZCOLS + kt + ch * 8);
            *reinterpret_cast<half8*>(&As[r][ch * 8]) = av;
            float s = 0.f;
#pragma unroll
            for (int e = 0; e < 8; ++e) { const float f = (float)av[e]; s = fmaf(f, f, s); }
            ss[q] += s;
            *reinterpret_cast<s16x8*>(&Bs[r][ch * 8]) =
                *reinterpret_cast<const s16x8*>(Bt + (size_t)(n0 + r) * DZCOLS + kt + ch * 8);
        }
        __syncthreads();
#pragma unroll
        for (int ks = 0; ks < 64; ks += 32) {
            half8 af[4], bf[4];
#pragma unroll
            for (int m = 0; m < 4; ++m)
                af[m] = *reinterpret_cast<const half8*>(&As[wr * 64 + m * 16 + fr][ks + fq * 8]);
#pragma unroll
            for (int n = 0; n < 4; ++n)
                bf[n] = *reinterpret_cast<const half8*>(&Bs[wc * 64 + n * 16 + fr][ks + fq * 8]);
#pragma unroll
            for (int m = 0; m < 4; ++m)
#pragma unroll
                for (int n = 0; n < 4; ++n)
                    acc[m][n] = __builtin_amdgcn_mfma_f32_16x16x32_f16(af[m], bf[n], acc[m][n], 0, 0, 0);
        }
        __syncthreads();
    }

    // fused per-row RMS scale: thread t staged rows (t>>3)+q*32, cols ch=t&7
#pragma unroll
    for (int q = 0; q < 4; ++q) ssp[(t >> 3) + q * 32][t & 7] = ss[q];
    __syncthreads();
    if (t < 128) {
        float s = 0.f;
#pragma unroll
        for (int ch = 0; ch < 8; ++ch) s += ssp[t][ch];
        scl[t] = rsqrtf(s * (1.0f / 1024.0f) + 1e-5f);
    }
    __syncthreads();

#pragma unroll
    for (int m = 0; m < 4; ++m)
#pragma unroll
        for (int j = 0; j < 4; ++j) {
            const int rloc = wr * 64 + m * 16 + fq * 4 + j;
            const int row = m0 + rloc;
            const float sc = scl[rloc];
#pragma unroll
            for (int n = 0; n < 4; ++n) {
                const int col = n0 + wc * 64 + n * 16 + fr;
                C[(size_t)row * DMODEL + col] = acc[m][n][j] * sc;
            }
        }
}

// ---------------------------------------------------------------------------
extern "C" void kernel_launch(void* const* d_in, const int* in_sizes, int n_in,
                              void* d_out, int out_size, void* d_ws, size_t ws_size,
                              hipStream_t stream)
{
    const float* x         = (const float*)d_in[0];
    const float* W_in      = (const float*)d_in[1];
    const float* conv_w    = (const float*)d_in[2];
    const float* conv_b    = (const float*)d_in[3];
    const float* A_log     = (const float*)d_in[4];
    const float* dt_bias   = (const float*)d_in[5];
    const float* Dp        = (const float*)d_in[6];
    const float* init_conv = (const float*)d_in[7];
    const float* init_ssm  = (const float*)d_in[8];
    const float* norm_w    = (const float*)d_in[9];
    const float* W_out     = (const float*)d_in[10];
    float* out = (float*)d_out;

    // fp32 pool
    float* ws      = (float*)d_ws;
    float* dtraw   = ws;                                                       // M*8
    float* Acum    = dtraw + (size_t)MROWS * 8;                                // 262,144
    float* ctbuf   = Acum + (size_t)BATCHN * NHEADS * NCHUNK * CHK * 2;        // 4096
    float* stbuf   = ctbuf + (size_t)BATCHN * NHEADS * NCHUNK * 2;             // 4,194,304
    float* SinBuf  = stbuf + (size_t)BATCHN * NCHUNK * NHEADS * HDIM * DSTATE * 2;
    // fp16 pool
    _Float16* zx      = (_Float16*)(SinBuf + (size_t)BATCHN * NCHUNK * NHEADS * HDIM * DSTATE * 2);
    _Float16* convout = zx + (size_t)MROWS * DIP;
    _Float16* A2      = convout + (size_t)MROWS * CONVD;
    _Float16* Bt16    = A2 + (size_t)MROWS * DZCOLS;
    _Float16* Wot     = Bt16 + (size_t)NPAD * DMODEL;
    // total ~140 MB

    k_cvt_win<<<dim3(NPAD), dim3(256), 0, stream>>>(W_in, Bt16);
    k_cvt_wout<<<dim3(DZCOLS), dim3(256), 0, stream>>>(W_out, norm_w, Wot);

    k_gemm_in<<<dim3(NPAD / 128, MROWS / 128), dim3(256), 0, stream>>>(
        x, Bt16, zx, dtraw);

    const int convThreads = MROWS * (CONVD / 8);
    k_conv<<<(convThreads + 255) / 256, dim3(256), 0, stream>>>(
        zx, conv_w, conv_b, init_conv, convout);

    k_states<<<dim3(NCHUNK, NHEADS, BATCHN), dim3(256), 0, stream>>>(
        dtraw, convout, A_log, dt_bias, Acum, ctbuf, stbuf);

    k_scan<<<dim3(NHEADS, BATCHN), dim3(1024), 0, stream>>>(ctbuf, stbuf, init_ssm, SinBuf);

    k_yout<<<dim3(NCHUNK, NHEADS, BATCHN), dim3(256), 0, stream>>>(
        convout, Acum, SinBuf, Dp, dt_bias, dtraw, zx, A2);

    k_gemm_out<<<dim3(DMODEL / 128, MROWS / 128), dim3(256), 0, stream>>>(
        A2, Wot, out);
}

// Round 10
// 227.045 us; speedup vs baseline: 3.0535x; 1.0379x over previous
//
#include <hip/hip_runtime.h>
#include <math.h>

#define BATCHN 4
#define SEQL   4096
#define DMODEL 256
#define DIP    1576      // in-proj output cols
#define DINNER 512
#define DZCOLS 1024      // 2*D_INNER
#define CONVD  544
#define NHEADS 8
#define HDIM   64
#define DSTATE 16
#define CHK    64
#define NCHUNK 64
#define MROWS  (BATCHN*SEQL)
#define NPAD   1664      // 13*128, padded N for in-proj GEMM

typedef _Float16 half8 __attribute__((ext_vector_type(8)));
typedef _Float16 half4 __attribute__((ext_vector_type(4)));
typedef short    s16x8 __attribute__((ext_vector_type(8)));
typedef float    f32x4 __attribute__((ext_vector_type(4)));

__device__ __forceinline__ float clip6f(float x) { return fminf(fmaxf(x, 0.0f), 6.0f); }

// ---------------------------------------------------------------------------
// x[M,256] fp32 -> A16 fp16 (streaming cvt; keeps GEMM staging single-load)
// ---------------------------------------------------------------------------
__global__ __launch_bounds__(256) void k_cvt_x(const float* __restrict__ X,
                                               _Float16* __restrict__ A)
{
    const int gid = blockIdx.x * 256 + threadIdx.x;   // M*256/8 threads
    const float4 a = *reinterpret_cast<const float4*>(X + (size_t)gid * 8);
    const float4 b = *reinterpret_cast<const float4*>(X + (size_t)gid * 8 + 4);
    half8 h;
    h[0] = (_Float16)a.x; h[1] = (_Float16)a.y; h[2] = (_Float16)a.z; h[3] = (_Float16)a.w;
    h[4] = (_Float16)b.x; h[5] = (_Float16)b.y; h[6] = (_Float16)b.z; h[7] = (_Float16)b.w;
    *reinterpret_cast<half8*>(A + (size_t)gid * 8) = h;
}

// W_in[256,1576] -> Bt[1664,256] fp16 (zero pad n>=1576)
__global__ __launch_bounds__(256) void k_cvt_win(const float* __restrict__ W,
                                                 _Float16* __restrict__ Bt)
{
    const int gid = blockIdx.x * 256 + threadIdx.x;   // NPAD*256 threads
    const int k = gid & 255, n = gid >> 8;
    const float v = (n < DIP) ? W[(size_t)k * DIP + n] : 0.0f;
    Bt[gid] = (_Float16)v;
}

// W_out[1024,256]*norm_w[k] -> Wot[256,1024] fp16
__global__ __launch_bounds__(256) void k_cvt_wout(const float* __restrict__ W,
                                                  const float* __restrict__ nw,
                                                  _Float16* __restrict__ Bt)
{
    const int gid = blockIdx.x * 256 + threadIdx.x;   // 256*1024 threads
    const int k = gid & 1023, n = gid >> 10;
    Bt[gid] = (_Float16)(W[(size_t)k * DMODEL + n] * nw[k]);
}

// ---------------------------------------------------------------------------
// K1: zx16[M,1576](fp16) = A16[M,256] @ Bt^T; dt_raw cols -> fp32 dtraw
//     (fp16 A staging = 1 load/thread; round-8 proven structure)
// ---------------------------------------------------------------------------
__global__ __launch_bounds__(256) void k_gemm_in(const _Float16* __restrict__ A,
                                                 const _Float16* __restrict__ Bt,
                                                 _Float16* __restrict__ zx,
                                                 float* __restrict__ dtraw)
{
    __shared__ _Float16 As[128][72];
    __shared__ _Float16 Bs[128][72];
    const int t  = threadIdx.x;
    const int m0 = blockIdx.y * 128;
    const int n0 = blockIdx.x * 128;
    const int lane = t & 63, wid = t >> 6;
    const int wr = wid >> 1, wc = wid & 1;
    const int fr = lane & 15, fq = lane >> 4;

    f32x4 acc[4][4];
#pragma unroll
    for (int m = 0; m < 4; ++m)
#pragma unroll
        for (int n = 0; n < 4; ++n)
#pragma unroll
            for (int e = 0; e < 4; ++e) acc[m][n][e] = 0.0f;

    for (int kt = 0; kt < DMODEL; kt += 64) {
#pragma unroll
        for (int q = 0; q < 4; ++q) {
            const int idx = t + q * 256;
            const int r = idx >> 3, ch = idx & 7;
            *reinterpret_cast<s16x8*>(&As[r][ch * 8]) =
                *reinterpret_cast<const s16x8*>(A + (size_t)(m0 + r) * DMODEL + kt + ch * 8);
            *reinterpret_cast<s16x8*>(&Bs[r][ch * 8]) =
                *reinterpret_cast<const s16x8*>(Bt + (size_t)(n0 + r) * DMODEL + kt + ch * 8);
        }
        __syncthreads();
#pragma unroll
        for (int ks = 0; ks < 64; ks += 32) {
            half8 af[4], bf[4];
#pragma unroll
            for (int m = 0; m < 4; ++m)
                af[m] = *reinterpret_cast<const half8*>(&As[wr * 64 + m * 16 + fr][ks + fq * 8]);
#pragma unroll
            for (int n = 0; n < 4; ++n)
                bf[n] = *reinterpret_cast<const half8*>(&Bs[wc * 64 + n * 16 + fr][ks + fq * 8]);
#pragma unroll
            for (int m = 0; m < 4; ++m)
#pragma unroll
                for (int n = 0; n < 4; ++n)
                    acc[m][n] = __builtin_amdgcn_mfma_f32_16x16x32_f16(af[m], bf[n], acc[m][n], 0, 0, 0);
        }
        __syncthreads();
    }

#pragma unroll
    for (int m = 0; m < 4; ++m)
#pragma unroll
        for (int j = 0; j < 4; ++j) {
            const int row = m0 + wr * 64 + m * 16 + fq * 4 + j;
#pragma unroll
            for (int n = 0; n < 4; ++n) {
                const int col = n0 + wc * 64 + n * 16 + fr;
                const float v = acc[m][n][j];
                if (col < DIP) {
                    zx[(size_t)row * DIP + col] = (_Float16)v;
                    if (col >= 3 * DINNER + 2 * DSTATE)        // 1568..1575: dt_raw fp32
                        dtraw[(size_t)row * 8 + (col - (3 * DINNER + 2 * DSTATE))] = v;
                }
            }
        }
}

// ---------------------------------------------------------------------------
// K2: causal conv1d (K=4) over xBC cols of zx16, relu6 -> convout16[M,544]
// ---------------------------------------------------------------------------
__global__ __launch_bounds__(256) void k_conv(const _Float16* __restrict__ zx,
                                              const float* __restrict__ conv_w,
                                              const float* __restrict__ conv_b,
                                              const float* __restrict__ init_conv,
                                              _Float16* __restrict__ convout)
{
    const int NC8 = CONVD / 8; // 68
    const int gid = blockIdx.x * 256 + threadIdx.x;
    if (gid >= MROWS * NC8) return;
    const int row  = gid / NC8;
    const int c    = (gid % NC8) * 8;
    const int b    = row / SEQL;
    const int tpos = row % SEQL;
    float acc[8];
    {
        const float4 b0 = *reinterpret_cast<const float4*>(conv_b + c);
        const float4 b1 = *reinterpret_cast<const float4*>(conv_b + c + 4);
        acc[0] = b0.x; acc[1] = b0.y; acc[2] = b0.z; acc[3] = b0.w;
        acc[4] = b1.x; acc[5] = b1.y; acc[6] = b1.z; acc[7] = b1.w;
    }
#pragma unroll
    for (int j = 0; j < 4; ++j) {
        const int srct = tpos - 3 + j;
        float v[8];
        if (srct >= 0) {
            const half8 hv = *reinterpret_cast<const half8*>(
                zx + (size_t)(b * SEQL + srct) * DIP + DZCOLS + c);
#pragma unroll
            for (int e = 0; e < 8; ++e) v[e] = (float)hv[e];
        } else {
            const float* ip = init_conv + (size_t)(tpos + 1 + j) * CONVD + c;
            const float4 i0 = *reinterpret_cast<const float4*>(ip);
            const float4 i1 = *reinterpret_cast<const float4*>(ip + 4);
            v[0] = i0.x; v[1] = i0.y; v[2] = i0.z; v[3] = i0.w;
            v[4] = i1.x; v[5] = i1.y; v[6] = i1.z; v[7] = i1.w;
        }
        const float* wp = conv_w + (size_t)j * CONVD + c;
        const float4 w0 = *reinterpret_cast<const float4*>(wp);
        const float4 w1 = *reinterpret_cast<const float4*>(wp + 4);
        const float w[8] = {w0.x, w0.y, w0.z, w0.w, w1.x, w1.y, w1.z, w1.w};
#pragma unroll
        for (int e = 0; e < 8; ++e) acc[e] = fmaf(w[e], v[e], acc[e]);
    }
    half8 hv;
#pragma unroll
    for (int e = 0; e < 8; ++e) hv[e] = (_Float16)clip6f(acc[e]);
    *reinterpret_cast<half8*>(convout + (size_t)row * CONVD + c) = hv;
}

// ---------------------------------------------------------------------------
// K3: per (b,h,chunk): A_cum (complex wave scan), chunk totals, local states
// ---------------------------------------------------------------------------
__global__ __launch_bounds__(256) void k_states(const float* __restrict__ dtraw,
                                                const _Float16* __restrict__ conv,
                                                const float* __restrict__ A_log,
                                                const float* __restrict__ dt_bias,
                                                float* __restrict__ Acum,
                                                float* __restrict__ ctbuf,
                                                float* __restrict__ st)
{
    const int c = blockIdx.x, h = blockIdx.y, b = blockIdx.z;
    __shared__ float wr[CHK], wi[CHK];
    __shared__ float xs[CHK][HDIM];
    __shared__ float Bsh[CHK][DSTATE];
    const int t = threadIdx.x;

#pragma unroll
    for (int q = 0; q < 2; ++q) {
        const int g = t + q * 256;
        const int l = g >> 3, p8 = (g & 7) * 8;
        const half8 hv = *reinterpret_cast<const half8*>(
            conv + (size_t)(b * SEQL + c * CHK + l) * CONVD + h * HDIM + p8);
#pragma unroll
        for (int e = 0; e < 8; ++e) xs[l][p8 + e] = (float)hv[e];
    }
    if (t < 128) {
        const int l = t >> 1, n8 = (t & 1) * 8;
        const half8 hv = *reinterpret_cast<const half8*>(
            conv + (size_t)(b * SEQL + c * CHK + l) * CONVD + DINNER + n8);
#pragma unroll
        for (int e = 0; e < 8; ++e) Bsh[l][n8 + e] = (float)hv[e];
    }

    if (t < 64) {
        const int l = t;
        const int row = b * SEQL + c * CHK + l;
        const float dtv = fminf(__expf(dtraw[(size_t)row * 8 + h] + dt_bias[h]), 6.0f);
        const float Ar = -__expf(A_log[2 * h]);
        const float Ai = A_log[2 * h + 1];
        float cr = Ar * dtv, ci = Ai * dtv;
#pragma unroll
        for (int off = 1; off < 64; off <<= 1) {
            const float pr = __shfl_up(cr, off);
            const float pi = __shfl_up(ci, off);
            if (l >= off) { cr += pr; ci += pi; }
        }
        const size_t aidx = ((((size_t)b * NHEADS + h) * NCHUNK + c) * CHK + l) * 2;
        Acum[aidx] = cr; Acum[aidx + 1] = ci;
        const float ctr = __shfl(cr, 63), cti = __shfl(ci, 63);
        if (l == 63) {
            const size_t ci2 = (((size_t)b * NHEADS + h) * NCHUNK + c) * 2;
            ctbuf[ci2] = ctr; ctbuf[ci2 + 1] = cti;
        }
        const float e = __expf(ctr - cr);
        float sn, cn; sincosf(cti - ci, &sn, &cn);
        wr[l] = e * cn * dtv;
        wi[l] = e * sn * dtv;
    }
    __syncthreads();

    const int p = t >> 2, n0 = (t & 3) * 4;
    float accr[4] = {0.f, 0.f, 0.f, 0.f};
    float acci[4] = {0.f, 0.f, 0.f, 0.f};
    for (int l = 0; l < CHK; ++l) {
        const float xv = xs[l][p];
        const float xr = xv * wr[l];
        const float xi = xv * wi[l];
#pragma unroll
        for (int j = 0; j < 4; ++j) {
            const float bb = Bsh[l][n0 + j];
            accr[j] = fmaf(bb, xr, accr[j]);
            acci[j] = fmaf(bb, xi, acci[j]);
        }
    }
    const size_t sidx = (((((size_t)b * NCHUNK + c) * NHEADS + h) * HDIM + p) * DSTATE + n0) * 2;
    float4 o0 = make_float4(accr[0], acci[0], accr[1], acci[1]);
    float4 o1 = make_float4(accr[2], acci[2], accr[3], acci[3]);
    *reinterpret_cast<float4*>(st + sidx)     = o0;
    *reinterpret_cast<float4*>(st + sidx + 4) = o1;
}

// ---------------------------------------------------------------------------
// K4: sequential inter-chunk complex scan
// ---------------------------------------------------------------------------
__global__ __launch_bounds__(1024) void k_scan(const float* __restrict__ ctbuf,
                                               const float* __restrict__ st,
                                               const float* __restrict__ init_ssm,
                                               float* __restrict__ Sin)
{
    const int h = blockIdx.x, b = blockIdx.y;
    __shared__ float Tr[NCHUNK], Ti[NCHUNK];
    const int t = threadIdx.x;
    if (t < NCHUNK) {
        const size_t ci2 = (((size_t)b * NHEADS + h) * NCHUNK + t) * 2;
        const float e = __expf(ctbuf[ci2]);
        float sn, cn; sincosf(ctbuf[ci2 + 1], &sn, &cn);
        Tr[t] = e * cn; Ti[t] = e * sn;
    }
    __syncthreads();
    const int p = t >> 4, n = t & 15;
    const size_t ii = (((size_t)h * HDIM + p) * DSTATE + n) * 2;
    float Sr = init_ssm[ii], Si = init_ssm[ii + 1];
    for (int z = 0; z < NCHUNK; ++z) {
        const size_t idx = (((((size_t)b * NCHUNK + z) * NHEADS + h) * HDIM + p) * DSTATE + n) * 2;
        Sin[idx] = Sr; Sin[idx + 1] = Si;
        const float sr = st[idx], si = st[idx + 1];
        const float tr = Tr[z], ti = Ti[z];
        const float nr = fmaf(tr, Sr, fmaf(-ti, Si, sr));
        const float ni = fmaf(tr, Si, fmaf(ti, Sr, si));
        Sr = nr; Si = ni;
    }
}

// ---------------------------------------------------------------------------
// K5 (MFMA): Y = G @ xdt + E*(C @ S^T); D residual; gate clip6(z);
//            yz -> fp16 A2[M,1024]; conv/zx inputs fp16
// ---------------------------------------------------------------------------
__global__ __launch_bounds__(256) void k_yout(const _Float16* __restrict__ conv,
                                              const float* __restrict__ Acum,
                                              const float* __restrict__ Sin,
                                              const float* __restrict__ Dp,
                                              const float* __restrict__ dt_bias,
                                              const float* __restrict__ dtraw,
                                              const _Float16* __restrict__ zx,
                                              _Float16* __restrict__ A2)
{
    const int c = blockIdx.x, h = blockIdx.y, b = blockIdx.z;
    __shared__ _Float16 Csh[64][40];   // A-operand (row l, K=n, zero-padded 16..31)
    __shared__ _Float16 Bsh[64][40];   // B-operand (col s, K=n)
    __shared__ _Float16 Srs[64][40];   // B-operand (col p, K=n)
    __shared__ _Float16 Sis[64][40];
    __shared__ _Float16 Xt[64][72];    // B-operand (col p, K=s): x[s][p]*dt[s]
    __shared__ _Float16 Gr[64][72];    // A-operand (row l, K=s)
    __shared__ _Float16 Gi[64][72];
    __shared__ float dts[64], cumr[64], sl_[64], cl_[64], Er[64], Ei[64];
    const int t = threadIdx.x;
    const int lane = t & 63, w = t >> 6;
    const int fr = lane & 15, fq = lane >> 4;
    const int rowb = b * SEQL + c * CHK;

    if (t < 64) {
        const int l = t, row = rowb + l;
        dts[l] = fminf(__expf(dtraw[(size_t)row * 8 + h] + dt_bias[h]), 6.0f);
        const size_t aidx = ((((size_t)b * NHEADS + h) * NCHUNK + c) * CHK + l) * 2;
        const float cr = Acum[aidx], ci = Acum[aidx + 1];
        cumr[l] = cr;
        float sn, cn; sincosf(ci, &sn, &cn);
        sl_[l] = sn; cl_[l] = cn;
        const float e = __expf(cr);
        Er[l] = e * cn; Ei[l] = e * sn;
    }
    {   // B, C (fp16 direct), S_in (fp32->fp16) tiles + zero pads
        const int l = t >> 2, n4 = (t & 3) * 4;
        const _Float16* cp = conv + (size_t)(rowb + l) * CONVD + DINNER;
        const half4 bv = *reinterpret_cast<const half4*>(cp + n4);
        const half4 cv = *reinterpret_cast<const half4*>(cp + DSTATE + n4);
        Bsh[l][n4 + 0] = bv[0]; Bsh[l][n4 + 1] = bv[1];
        Bsh[l][n4 + 2] = bv[2]; Bsh[l][n4 + 3] = bv[3];
        Csh[l][n4 + 0] = cv[0]; Csh[l][n4 + 1] = cv[1];
        Csh[l][n4 + 2] = cv[2]; Csh[l][n4 + 3] = cv[3];
        const float* sp = Sin + ((((size_t)b * NCHUNK + c) * NHEADS + h) * HDIM + l) * (DSTATE * 2) + n4 * 2;
        const float4 s0 = *reinterpret_cast<const float4*>(sp);
        const float4 s1 = *reinterpret_cast<const float4*>(sp + 4);
        Srs[l][n4 + 0] = (_Float16)s0.x; Sis[l][n4 + 0] = (_Float16)s0.y;
        Srs[l][n4 + 1] = (_Float16)s0.z; Sis[l][n4 + 1] = (_Float16)s0.w;
        Srs[l][n4 + 2] = (_Float16)s1.x; Sis[l][n4 + 2] = (_Float16)s1.y;
        Srs[l][n4 + 3] = (_Float16)s1.z; Sis[l][n4 + 3] = (_Float16)s1.w;
        const int z0 = 16 + (t & 3) * 4;
#pragma unroll
        for (int e = 0; e < 4; ++e) {
            Bsh[l][z0 + e] = (_Float16)0.0f;
            Csh[l][z0 + e] = (_Float16)0.0f;
            Srs[l][z0 + e] = (_Float16)0.0f;
            Sis[l][z0 + e] = (_Float16)0.0f;
        }
    }
    __syncthreads();

    // Xt[p][s] = x[s][p]*dt[s]  (fp16 source)
#pragma unroll
    for (int q = 0; q < 2; ++q) {
        const int g = t + q * 256;
        const int l = g >> 3, p8 = (g & 7) * 8;
        const half8 hv = *reinterpret_cast<const half8*>(
            conv + (size_t)(rowb + l) * CONVD + h * HDIM + p8);
        const float d = dts[l];
#pragma unroll
        for (int e = 0; e < 8; ++e)
            Xt[p8 + e][l] = (_Float16)((float)hv[e] * d);
    }

    // CB = C.B^T  (wave w owns rows [w*16, w*16+16))
    const half8 afC = *reinterpret_cast<const half8*>(&Csh[w * 16 + fr][fq * 8]);
    f32x4 cb[4];
#pragma unroll
    for (int nf = 0; nf < 4; ++nf) {
        const half8 bfB = *reinterpret_cast<const half8*>(&Bsh[nf * 16 + fr][fq * 8]);
        f32x4 z = {0.f, 0.f, 0.f, 0.f};
        cb[nf] = __builtin_amdgcn_mfma_f32_16x16x32_f16(afC, bfB, z, 0, 0, 0);
    }
    // G = CB * exp(segsum)  (mask s<=l), store fp16
#pragma unroll
    for (int nf = 0; nf < 4; ++nf) {
        const int s = nf * 16 + fr;
        const float crs = cumr[s], sls = sl_[s], cls = cl_[s];
#pragma unroll
        for (int j = 0; j < 4; ++j) {
            const int l = w * 16 + fq * 4 + j;
            const float dr = fminf(cumr[l] - crs, 0.0f);
            const float e = __expf(dr);
            const float cd = cl_[l] * cls + sl_[l] * sls;
            const float sd = sl_[l] * cls - cl_[l] * sls;
            const float ge = (s <= l) ? cb[nf][j] * e : 0.0f;
            Gr[l][s] = (_Float16)(ge * cd);
            Gi[l][s] = (_Float16)(ge * sd);
        }
    }
    __syncthreads();

    // Y_diag = G @ xdt
    f32x4 accr[4], acci[4];
#pragma unroll
    for (int nf = 0; nf < 4; ++nf)
#pragma unroll
        for (int e = 0; e < 4; ++e) { accr[nf][e] = 0.f; acci[nf][e] = 0.f; }
#pragma unroll
    for (int ks = 0; ks < 64; ks += 32) {
        const half8 ar = *reinterpret_cast<const half8*>(&Gr[w * 16 + fr][ks + fq * 8]);
        const half8 ai = *reinterpret_cast<const half8*>(&Gi[w * 16 + fr][ks + fq * 8]);
#pragma unroll
        for (int nf = 0; nf < 4; ++nf) {
            const half8 bx = *reinterpret_cast<const half8*>(&Xt[nf * 16 + fr][ks + fq * 8]);
            accr[nf] = __builtin_amdgcn_mfma_f32_16x16x32_f16(ar, bx, accr[nf], 0, 0, 0);
            acci[nf] = __builtin_amdgcn_mfma_f32_16x16x32_f16(ai, bx, acci[nf], 0, 0, 0);
        }
    }
    // Y_off inner: O = C @ S^T
    f32x4 orr[4], oii[4];
#pragma unroll
    for (int nf = 0; nf < 4; ++nf) {
        const half8 br = *reinterpret_cast<const half8*>(&Srs[nf * 16 + fr][fq * 8]);
        const half8 bi = *reinterpret_cast<const half8*>(&Sis[nf * 16 + fr][fq * 8]);
        f32x4 z = {0.f, 0.f, 0.f, 0.f};
        orr[nf] = __builtin_amdgcn_mfma_f32_16x16x32_f16(afC, br, z, 0, 0, 0);
        oii[nf] = __builtin_amdgcn_mfma_f32_16x16x32_f16(afC, bi, z, 0, 0, 0);
    }

    // epilogue: Y = Ydiag + E*O; D residual; z-gate; fp16 store
    const float dcoef = Dp[2 * h];
#pragma unroll
    for (int nf = 0; nf < 4; ++nf) {
        const int p = nf * 16 + fr;
#pragma unroll
        for (int j = 0; j < 4; ++j) {
            const int l = w * 16 + fq * 4 + j;
            const int row = rowb + l;
            const float er = Er[l], ei = Ei[l];
            float yr = accr[nf][j] + er * orr[nf][j] - ei * oii[nf][j];
            float yi = acci[nf][j] + er * oii[nf][j] + ei * orr[nf][j];
            const float xinv = (float)conv[(size_t)row * CONVD + h * HDIM + p];
            yr = fmaf(xinv, dcoef, yr);
            const size_t zidx = (size_t)row * DIP + h * 128 + p;
            const float zr = (float)zx[zidx], zi2 = (float)zx[zidx + 64];
            const size_t aidx2 = (size_t)row * DZCOLS + h * 128 + p;
            A2[aidx2]      = (_Float16)(yr * clip6f(zr));
            A2[aidx2 + 64] = (_Float16)(yi * clip6f(zi2));
        }
    }
}

// ---------------------------------------------------------------------------
// K6: out[M,256](fp32) = (A2 * rms_scale_row) @ Wot^T, RMS fused in-kernel
// ---------------------------------------------------------------------------
__global__ __launch_bounds__(256) void k_gemm_out(const _Float16* __restrict__ A,
                                                  const _Float16* __restrict__ Bt,
                                                  float* __restrict__ C)
{
    __shared__ _Float16 As[128][72];
    __shared__ _Float16 Bs[128][72];
    __shared__ float ssp[128][8];
    __shared__ float scl[128];
    const int t  = threadIdx.x;
    const int m0 = blockIdx.y * 128;
    const int n0 = blockIdx.x * 128;
    const int lane = t & 63, wid = t >> 6;
    const int wr = wid >> 1, wc = wid & 1;
    const int fr = lane & 15, fq = lane >> 4;

    f32x4 acc[4][4];
#pragma unroll
    for (int m = 0; m < 4; ++m)
#pragma unroll
        for (int n = 0; n < 4; ++n)
#pragma unroll
            for (int e = 0; e < 4; ++e) acc[m][n][e] = 0.0f;
    float ss[4] = {0.f, 0.f, 0.f, 0.f};

    for (int kt = 0; kt < DZCOLS; kt += 64) {
#pragma unroll
        for (int q = 0; q < 4; ++q) {
            const int idx = t + q * 256;
            const int r = idx >> 3, ch = idx & 7;
            const half8 av = *reinterpret_cast<const half8*>(
                A + (size_t)(m0 + r) * DZCOLS + kt + ch * 8);
            *reinterpret_cast<half8*>(&As[r][ch * 8]) = av;
            float s = 0.f;
#pragma unroll
            for (int e = 0; e < 8; ++e) { const float f = (float)av[e]; s = fmaf(f, f, s); }
            ss[q] += s;
            *reinterpret_cast<s16x8*>(&Bs[r][ch * 8]) =
                *reinterpret_cast<const s16x8*>(Bt + (size_t)(n0 + r) * DZCOLS + kt + ch * 8);
        }
        __syncthreads();
#pragma unroll
        for (int ks = 0; ks < 64; ks += 32) {
            half8 af[4], bf[4];
#pragma unroll
            for (int m = 0; m < 4; ++m)
                af[m] = *reinterpret_cast<const half8*>(&As[wr * 64 + m * 16 + fr][ks + fq * 8]);
#pragma unroll
            for (int n = 0; n < 4; ++n)
                bf[n] = *reinterpret_cast<const half8*>(&Bs[wc * 64 + n * 16 + fr][ks + fq * 8]);
#pragma unroll
            for (int m = 0; m < 4; ++m)
#pragma unroll
                for (int n = 0; n < 4; ++n)
                    acc[m][n] = __builtin_amdgcn_mfma_f32_16x16x32_f16(af[m], bf[n], acc[m][n], 0, 0, 0);
        }
        __syncthreads();
    }

    // fused per-row RMS scale: thread t staged rows (t>>3)+q*32, cols ch=t&7
#pragma unroll
    for (int q = 0; q < 4; ++q) ssp[(t >> 3) + q * 32][t & 7] = ss[q];
    __syncthreads();
    if (t < 128) {
        float s = 0.f;
#pragma unroll
        for (int ch = 0; ch < 8; ++ch) s += ssp[t][ch];
        scl[t] = rsqrtf(s * (1.0f / 1024.0f) + 1e-5f);
    }
    __syncthreads();

#pragma unroll
    for (int m = 0; m < 4; ++m)
#pragma unroll
        for (int j = 0; j < 4; ++j) {
            const int rloc = wr * 64 + m * 16 + fq * 4 + j;
            const int row = m0 + rloc;
            const float sc = scl[rloc];
#pragma unroll
            for (int n = 0; n < 4; ++n) {
                const int col = n0 + wc * 64 + n * 16 + fr;
                C[(size_t)row * DMODEL + col] = acc[m][n][j] * sc;
            }
        }
}

// ---------------------------------------------------------------------------
extern "C" void kernel_launch(void* const* d_in, const int* in_sizes, int n_in,
                              void* d_out, int out_size, void* d_ws, size_t ws_size,
                              hipStream_t stream)
{
    const float* x         = (const float*)d_in[0];
    const float* W_in      = (const float*)d_in[1];
    const float* conv_w    = (const float*)d_in[2];
    const float* conv_b    = (const float*)d_in[3];
    const float* A_log     = (const float*)d_in[4];
    const float* dt_bias   = (const float*)d_in[5];
    const float* Dp        = (const float*)d_in[6];
    const float* init_conv = (const float*)d_in[7];
    const float* init_ssm  = (const float*)d_in[8];
    const float* norm_w    = (const float*)d_in[9];
    const float* W_out     = (const float*)d_in[10];
    float* out = (float*)d_out;

    // fp32 pool
    float* ws      = (float*)d_ws;
    float* dtraw   = ws;                                                       // M*8
    float* Acum    = dtraw + (size_t)MROWS * 8;                                // 262,144
    float* ctbuf   = Acum + (size_t)BATCHN * NHEADS * NCHUNK * CHK * 2;        // 4096
    float* stbuf   = ctbuf + (size_t)BATCHN * NHEADS * NCHUNK * 2;             // 4,194,304
    float* SinBuf  = stbuf + (size_t)BATCHN * NCHUNK * NHEADS * HDIM * DSTATE * 2;
    // fp16 pool
    _Float16* zx      = (_Float16*)(SinBuf + (size_t)BATCHN * NCHUNK * NHEADS * HDIM * DSTATE * 2);
    _Float16* convout = zx + (size_t)MROWS * DIP;
    _Float16* A2      = convout + (size_t)MROWS * CONVD;
    _Float16* Bt16    = A2 + (size_t)MROWS * DZCOLS;
    _Float16* Wot     = Bt16 + (size_t)NPAD * DMODEL;
    _Float16* A16     = Wot + (size_t)DMODEL * DZCOLS;                         // M*256 halves
    // total ~149 MB

    k_cvt_x<<<dim3(MROWS * DMODEL / 8 / 256), dim3(256), 0, stream>>>(x, A16);
    k_cvt_win<<<dim3(NPAD), dim3(256), 0, stream>>>(W_in, Bt16);
    k_cvt_wout<<<dim3(DZCOLS), dim3(256), 0, stream>>>(W_out, norm_w, Wot);

    k_gemm_in<<<dim3(NPAD / 128, MROWS / 128), dim3(256), 0, stream>>>(
        A16, Bt16, zx, dtraw);

    const int convThreads = MROWS * (CONVD / 8);
    k_conv<<<(convThreads + 255) / 256, dim3(256), 0, stream>>>(
        zx, conv_w, conv_b, init_conv, convout);

    k_states<<<dim3(NCHUNK, NHEADS, BATCHN), dim3(256), 0, stream>>>(
        dtraw, convout, A_log, dt_bias, Acum, ctbuf, stbuf);

    k_scan<<<dim3(NHEADS, BATCHN), dim3(1024), 0, stream>>>(ctbuf, stbuf, init_ssm, SinBuf);

    k_yout<<<dim3(NCHUNK, NHEADS, BATCHN), dim3(256), 0, stream>>>(
        convout, Acum, SinBuf, Dp, dt_bias, dtraw, zx, A2);

    k_gemm_out<<<dim3(DMODEL / 128, MROWS / 128), dim3(256), 0, stream>>>(
        A2, Wot, out);
}

// Round 11
// 213.050 us; speedup vs baseline: 3.2540x; 1.0657x over previous
//
#include <hip/hip_runtime.h>
#include <math.h>

#define BATCHN 4
#define SEQL   4096
#define DMODEL 256
#define DIP    1576      // in-proj output cols
#define DINNER 512
#define DZCOLS 1024      // 2*D_INNER
#define CONVD  544
#define NHEADS 8
#define HDIM   64
#define DSTATE 16
#define CHK    64
#define NCHUNK 64
#define MROWS  (BATCHN*SEQL)
#define NPAD   1664      // 13*128, padded N for in-proj GEMM

typedef _Float16 half8 __attribute__((ext_vector_type(8)));
typedef _Float16 half4 __attribute__((ext_vector_type(4)));
typedef short    s16x8 __attribute__((ext_vector_type(8)));
typedef float    f32x4 __attribute__((ext_vector_type(4)));

__device__ __forceinline__ float clip6f(float x) { return fminf(fmaxf(x, 0.0f), 6.0f); }

// ---------------------------------------------------------------------------
// x[M,256] fp32 -> A16 fp16 (streaming cvt; keeps GEMM staging single-load)
// ---------------------------------------------------------------------------
__global__ __launch_bounds__(256) void k_cvt_x(const float* __restrict__ X,
                                               _Float16* __restrict__ A)
{
    const int gid = blockIdx.x * 256 + threadIdx.x;   // M*256/8 threads
    const float4 a = *reinterpret_cast<const float4*>(X + (size_t)gid * 8);
    const float4 b = *reinterpret_cast<const float4*>(X + (size_t)gid * 8 + 4);
    half8 h;
    h[0] = (_Float16)a.x; h[1] = (_Float16)a.y; h[2] = (_Float16)a.z; h[3] = (_Float16)a.w;
    h[4] = (_Float16)b.x; h[5] = (_Float16)b.y; h[6] = (_Float16)b.z; h[7] = (_Float16)b.w;
    *reinterpret_cast<half8*>(A + (size_t)gid * 8) = h;
}

// W_in[256,1576] -> Bt[1664,256] fp16 (zero pad n>=1576)
__global__ __launch_bounds__(256) void k_cvt_win(const float* __restrict__ W,
                                                 _Float16* __restrict__ Bt)
{
    const int gid = blockIdx.x * 256 + threadIdx.x;   // NPAD*256 threads
    const int k = gid & 255, n = gid >> 8;
    const float v = (n < DIP) ? W[(size_t)k * DIP + n] : 0.0f;
    Bt[gid] = (_Float16)v;
}

// W_out[1024,256]*norm_w[k] -> Wot[256,1024] fp16
__global__ __launch_bounds__(256) void k_cvt_wout(const float* __restrict__ W,
                                                  const float* __restrict__ nw,
                                                  _Float16* __restrict__ Bt)
{
    const int gid = blockIdx.x * 256 + threadIdx.x;   // 256*1024 threads
    const int k = gid & 1023, n = gid >> 10;
    Bt[gid] = (_Float16)(W[(size_t)k * DMODEL + n] * nw[k]);
}

// ---------------------------------------------------------------------------
// K1: zx16[M,1576](fp16) = A16[M,256] @ Bt^T; dt_raw cols -> fp32 dtraw
//     1D grid + XCD swizzle: 16 consecutive m-panels per XCD -> A L2-resident
// ---------------------------------------------------------------------------
__global__ __launch_bounds__(256) void k_gemm_in(const _Float16* __restrict__ A,
                                                 const _Float16* __restrict__ Bt,
                                                 _Float16* __restrict__ zx,
                                                 float* __restrict__ dtraw)
{
    __shared__ _Float16 As[128][72];
    __shared__ _Float16 Bs[128][72];
    const int t  = threadIdx.x;
    // XCD-aware swizzle: nwg = 1664 = 8 XCDs * 208; bijective (nwg%8==0)
    const int orig = blockIdx.x;
    const int nid  = (orig & 7) * (13 * (MROWS / 128) / 8) + (orig >> 3);
    const int m0 = (nid / 13) * 128;
    const int n0 = (nid % 13) * 128;
    const int lane = t & 63, wid = t >> 6;
    const int wr = wid >> 1, wc = wid & 1;
    const int fr = lane & 15, fq = lane >> 4;

    f32x4 acc[4][4];
#pragma unroll
    for (int m = 0; m < 4; ++m)
#pragma unroll
        for (int n = 0; n < 4; ++n)
#pragma unroll
            for (int e = 0; e < 4; ++e) acc[m][n][e] = 0.0f;

    for (int kt = 0; kt < DMODEL; kt += 64) {
#pragma unroll
        for (int q = 0; q < 4; ++q) {
            const int idx = t + q * 256;
            const int r = idx >> 3, ch = idx & 7;
            *reinterpret_cast<s16x8*>(&As[r][ch * 8]) =
                *reinterpret_cast<const s16x8*>(A + (size_t)(m0 + r) * DMODEL + kt + ch * 8);
            *reinterpret_cast<s16x8*>(&Bs[r][ch * 8]) =
                *reinterpret_cast<const s16x8*>(Bt + (size_t)(n0 + r) * DMODEL + kt + ch * 8);
        }
        __syncthreads();
#pragma unroll
        for (int ks = 0; ks < 64; ks += 32) {
            half8 af[4], bf[4];
#pragma unroll
            for (int m = 0; m < 4; ++m)
                af[m] = *reinterpret_cast<const half8*>(&As[wr * 64 + m * 16 + fr][ks + fq * 8]);
#pragma unroll
            for (int n = 0; n < 4; ++n)
                bf[n] = *reinterpret_cast<const half8*>(&Bs[wc * 64 + n * 16 + fr][ks + fq * 8]);
#pragma unroll
            for (int m = 0; m < 4; ++m)
#pragma unroll
                for (int n = 0; n < 4; ++n)
                    acc[m][n] = __builtin_amdgcn_mfma_f32_16x16x32_f16(af[m], bf[n], acc[m][n], 0, 0, 0);
        }
        __syncthreads();
    }

#pragma unroll
    for (int m = 0; m < 4; ++m)
#pragma unroll
        for (int j = 0; j < 4; ++j) {
            const int row = m0 + wr * 64 + m * 16 + fq * 4 + j;
#pragma unroll
            for (int n = 0; n < 4; ++n) {
                const int col = n0 + wc * 64 + n * 16 + fr;
                const float v = acc[m][n][j];
                if (col < DIP) {
                    zx[(size_t)row * DIP + col] = (_Float16)v;
                    if (col >= 3 * DINNER + 2 * DSTATE)        // 1568..1575: dt_raw fp32
                        dtraw[(size_t)row * 8 + (col - (3 * DINNER + 2 * DSTATE))] = v;
                }
            }
        }
}

// ---------------------------------------------------------------------------
// K2: causal conv1d (K=4) over xBC cols of zx16, relu6 -> convout16[M,544]
// ---------------------------------------------------------------------------
__global__ __launch_bounds__(256) void k_conv(const _Float16* __restrict__ zx,
                                              const float* __restrict__ conv_w,
                                              const float* __restrict__ conv_b,
                                              const float* __restrict__ init_conv,
                                              _Float16* __restrict__ convout)
{
    const int NC8 = CONVD / 8; // 68
    const int gid = blockIdx.x * 256 + threadIdx.x;
    if (gid >= MROWS * NC8) return;
    const int row  = gid / NC8;
    const int c    = (gid % NC8) * 8;
    const int b    = row / SEQL;
    const int tpos = row % SEQL;
    float acc[8];
    {
        const float4 b0 = *reinterpret_cast<const float4*>(conv_b + c);
        const float4 b1 = *reinterpret_cast<const float4*>(conv_b + c + 4);
        acc[0] = b0.x; acc[1] = b0.y; acc[2] = b0.z; acc[3] = b0.w;
        acc[4] = b1.x; acc[5] = b1.y; acc[6] = b1.z; acc[7] = b1.w;
    }
#pragma unroll
    for (int j = 0; j < 4; ++j) {
        const int srct = tpos - 3 + j;
        float v[8];
        if (srct >= 0) {
            const half8 hv = *reinterpret_cast<const half8*>(
                zx + (size_t)(b * SEQL + srct) * DIP + DZCOLS + c);
#pragma unroll
            for (int e = 0; e < 8; ++e) v[e] = (float)hv[e];
        } else {
            const float* ip = init_conv + (size_t)(tpos + 1 + j) * CONVD + c;
            const float4 i0 = *reinterpret_cast<const float4*>(ip);
            const float4 i1 = *reinterpret_cast<const float4*>(ip + 4);
            v[0] = i0.x; v[1] = i0.y; v[2] = i0.z; v[3] = i0.w;
            v[4] = i1.x; v[5] = i1.y; v[6] = i1.z; v[7] = i1.w;
        }
        const float* wp = conv_w + (size_t)j * CONVD + c;
        const float4 w0 = *reinterpret_cast<const float4*>(wp);
        const float4 w1 = *reinterpret_cast<const float4*>(wp + 4);
        const float w[8] = {w0.x, w0.y, w0.z, w0.w, w1.x, w1.y, w1.z, w1.w};
#pragma unroll
        for (int e = 0; e < 8; ++e) acc[e] = fmaf(w[e], v[e], acc[e]);
    }
    half8 hv;
#pragma unroll
    for (int e = 0; e < 8; ++e) hv[e] = (_Float16)clip6f(acc[e]);
    *reinterpret_cast<half8*>(convout + (size_t)row * CONVD + c) = hv;
}

// ---------------------------------------------------------------------------
// K3: per (b,h,chunk): A_cum (complex wave scan), chunk totals, local states
// ---------------------------------------------------------------------------
__global__ __launch_bounds__(256) void k_states(const float* __restrict__ dtraw,
                                                const _Float16* __restrict__ conv,
                                                const float* __restrict__ A_log,
                                                const float* __restrict__ dt_bias,
                                                float* __restrict__ Acum,
                                                float* __restrict__ ctbuf,
                                                float* __restrict__ st)
{
    const int c = blockIdx.x, h = blockIdx.y, b = blockIdx.z;
    __shared__ float wr[CHK], wi[CHK];
    __shared__ float xs[CHK][HDIM];
    __shared__ float Bsh[CHK][DSTATE];
    const int t = threadIdx.x;

#pragma unroll
    for (int q = 0; q < 2; ++q) {
        const int g = t + q * 256;
        const int l = g >> 3, p8 = (g & 7) * 8;
        const half8 hv = *reinterpret_cast<const half8*>(
            conv + (size_t)(b * SEQL + c * CHK + l) * CONVD + h * HDIM + p8);
#pragma unroll
        for (int e = 0; e < 8; ++e) xs[l][p8 + e] = (float)hv[e];
    }
    if (t < 128) {
        const int l = t >> 1, n8 = (t & 1) * 8;
        const half8 hv = *reinterpret_cast<const half8*>(
            conv + (size_t)(b * SEQL + c * CHK + l) * CONVD + DINNER + n8);
#pragma unroll
        for (int e = 0; e < 8; ++e) Bsh[l][n8 + e] = (float)hv[e];
    }

    if (t < 64) {
        const int l = t;
        const int row = b * SEQL + c * CHK + l;
        const float dtv = fminf(__expf(dtraw[(size_t)row * 8 + h] + dt_bias[h]), 6.0f);
        const float Ar = -__expf(A_log[2 * h]);
        const float Ai = A_log[2 * h + 1];
        float cr = Ar * dtv, ci = Ai * dtv;
#pragma unroll
        for (int off = 1; off < 64; off <<= 1) {
            const float pr = __shfl_up(cr, off);
            const float pi = __shfl_up(ci, off);
            if (l >= off) { cr += pr; ci += pi; }
        }
        const size_t aidx = ((((size_t)b * NHEADS + h) * NCHUNK + c) * CHK + l) * 2;
        Acum[aidx] = cr; Acum[aidx + 1] = ci;
        const float ctr = __shfl(cr, 63), cti = __shfl(ci, 63);
        if (l == 63) {
            const size_t ci2 = (((size_t)b * NHEADS + h) * NCHUNK + c) * 2;
            ctbuf[ci2] = ctr; ctbuf[ci2 + 1] = cti;
        }
        const float e = __expf(ctr - cr);
        float sn, cn; sincosf(cti - ci, &sn, &cn);
        wr[l] = e * cn * dtv;
        wi[l] = e * sn * dtv;
    }
    __syncthreads();

    const int p = t >> 2, n0 = (t & 3) * 4;
    float accr[4] = {0.f, 0.f, 0.f, 0.f};
    float acci[4] = {0.f, 0.f, 0.f, 0.f};
    for (int l = 0; l < CHK; ++l) {
        const float xv = xs[l][p];
        const float xr = xv * wr[l];
        const float xi = xv * wi[l];
#pragma unroll
        for (int j = 0; j < 4; ++j) {
            const float bb = Bsh[l][n0 + j];
            accr[j] = fmaf(bb, xr, accr[j]);
            acci[j] = fmaf(bb, xi, acci[j]);
        }
    }
    const size_t sidx = (((((size_t)b * NCHUNK + c) * NHEADS + h) * HDIM + p) * DSTATE + n0) * 2;
    float4 o0 = make_float4(accr[0], acci[0], accr[1], acci[1]);
    float4 o1 = make_float4(accr[2], acci[2], accr[3], acci[3]);
    *reinterpret_cast<float4*>(st + sidx)     = o0;
    *reinterpret_cast<float4*>(st + sidx + 4) = o1;
}

// ---------------------------------------------------------------------------
// K4: sequential inter-chunk complex scan — 256 blocks x 128 thr (8x CU spread)
// ---------------------------------------------------------------------------
__global__ __launch_bounds__(128) void k_scan(const float* __restrict__ ctbuf,
                                              const float* __restrict__ st,
                                              const float* __restrict__ init_ssm,
                                              float* __restrict__ Sin)
{
    const int pg = blockIdx.x;          // 0..7 (HDIM/8 groups)
    const int h = blockIdx.y, b = blockIdx.z;
    __shared__ float Tr[NCHUNK], Ti[NCHUNK];
    const int t = threadIdx.x;
    if (t < NCHUNK) {
        const size_t ci2 = (((size_t)b * NHEADS + h) * NCHUNK + t) * 2;
        const float e = __expf(ctbuf[ci2]);
        float sn, cn; sincosf(ctbuf[ci2 + 1], &sn, &cn);
        Tr[t] = e * cn; Ti[t] = e * sn;
    }
    __syncthreads();
    const int p = pg * 8 + (t >> 4), n = t & 15;
    const size_t ii = (((size_t)h * HDIM + p) * DSTATE + n) * 2;
    float Sr = init_ssm[ii], Si = init_ssm[ii + 1];
    for (int z = 0; z < NCHUNK; ++z) {
        const size_t idx = (((((size_t)b * NCHUNK + z) * NHEADS + h) * HDIM + p) * DSTATE + n) * 2;
        Sin[idx] = Sr; Sin[idx + 1] = Si;
        const float sr = st[idx], si = st[idx + 1];
        const float tr = Tr[z], ti = Ti[z];
        const float nr = fmaf(tr, Sr, fmaf(-ti, Si, sr));
        const float ni = fmaf(tr, Si, fmaf(ti, Sr, si));
        Sr = nr; Si = ni;
    }
}

// ---------------------------------------------------------------------------
// K5 (MFMA): Y = G @ xdt + E*(C @ S^T); D residual; gate clip6(z);
//            yz -> fp16 A2[M,1024]; conv/zx inputs fp16
// ---------------------------------------------------------------------------
__global__ __launch_bounds__(256) void k_yout(const _Float16* __restrict__ conv,
                                              const float* __restrict__ Acum,
                                              const float* __restrict__ Sin,
                                              const float* __restrict__ Dp,
                                              const float* __restrict__ dt_bias,
                                              const float* __restrict__ dtraw,
                                              const _Float16* __restrict__ zx,
                                              _Float16* __restrict__ A2)
{
    const int c = blockIdx.x, h = blockIdx.y, b = blockIdx.z;
    __shared__ _Float16 Csh[64][40];   // A-operand (row l, K=n, zero-padded 16..31)
    __shared__ _Float16 Bsh[64][40];   // B-operand (col s, K=n)
    __shared__ _Float16 Srs[64][40];   // B-operand (col p, K=n)
    __shared__ _Float16 Sis[64][40];
    __shared__ _Float16 Xt[64][72];    // B-operand (col p, K=s): x[s][p]*dt[s]
    __shared__ _Float16 Gr[64][72];    // A-operand (row l, K=s)
    __shared__ _Float16 Gi[64][72];
    __shared__ float dts[64], cumr[64], sl_[64], cl_[64], Er[64], Ei[64];
    const int t = threadIdx.x;
    const int lane = t & 63, w = t >> 6;
    const int fr = lane & 15, fq = lane >> 4;
    const int rowb = b * SEQL + c * CHK;

    if (t < 64) {
        const int l = t, row = rowb + l;
        dts[l] = fminf(__expf(dtraw[(size_t)row * 8 + h] + dt_bias[h]), 6.0f);
        const size_t aidx = ((((size_t)b * NHEADS + h) * NCHUNK + c) * CHK + l) * 2;
        const float cr = Acum[aidx], ci = Acum[aidx + 1];
        cumr[l] = cr;
        float sn, cn; sincosf(ci, &sn, &cn);
        sl_[l] = sn; cl_[l] = cn;
        const float e = __expf(cr);
        Er[l] = e * cn; Ei[l] = e * sn;
    }
    {   // B, C (fp16 direct), S_in (fp32->fp16) tiles + zero pads
        const int l = t >> 2, n4 = (t & 3) * 4;
        const _Float16* cp = conv + (size_t)(rowb + l) * CONVD + DINNER;
        const half4 bv = *reinterpret_cast<const half4*>(cp + n4);
        const half4 cv = *reinterpret_cast<const half4*>(cp + DSTATE + n4);
        Bsh[l][n4 + 0] = bv[0]; Bsh[l][n4 + 1] = bv[1];
        Bsh[l][n4 + 2] = bv[2]; Bsh[l][n4 + 3] = bv[3];
        Csh[l][n4 + 0] = cv[0]; Csh[l][n4 + 1] = cv[1];
        Csh[l][n4 + 2] = cv[2]; Csh[l][n4 + 3] = cv[3];
        const float* sp = Sin + ((((size_t)b * NCHUNK + c) * NHEADS + h) * HDIM + l) * (DSTATE * 2) + n4 * 2;
        const float4 s0 = *reinterpret_cast<const float4*>(sp);
        const float4 s1 = *reinterpret_cast<const float4*>(sp + 4);
        Srs[l][n4 + 0] = (_Float16)s0.x; Sis[l][n4 + 0] = (_Float16)s0.y;
        Srs[l][n4 + 1] = (_Float16)s0.z; Sis[l][n4 + 1] = (_Float16)s0.w;
        Srs[l][n4 + 2] = (_Float16)s1.x; Sis[l][n4 + 2] = (_Float16)s1.y;
        Srs[l][n4 + 3] = (_Float16)s1.z; Sis[l][n4 + 3] = (_Float16)s1.w;
        const int z0 = 16 + (t & 3) * 4;
#pragma unroll
        for (int e = 0; e < 4; ++e) {
            Bsh[l][z0 + e] = (_Float16)0.0f;
            Csh[l][z0 + e] = (_Float16)0.0f;
            Srs[l][z0 + e] = (_Float16)0.0f;
            Sis[l][z0 + e] = (_Float16)0.0f;
        }
    }
    __syncthreads();

    // Xt[p][s] = x[s][p]*dt[s]  (fp16 source)
#pragma unroll
    for (int q = 0; q < 2; ++q) {
        const int g = t + q * 256;
        const int l = g >> 3, p8 = (g & 7) * 8;
        const half8 hv = *reinterpret_cast<const half8*>(
            conv + (size_t)(rowb + l) * CONVD + h * HDIM + p8);
        const float d = dts[l];
#pragma unroll
        for (int e = 0; e < 8; ++e)
            Xt[p8 + e][l] = (_Float16)((float)hv[e] * d);
    }

    // CB = C.B^T  (wave w owns rows [w*16, w*16+16))
    const half8 afC = *reinterpret_cast<const half8*>(&Csh[w * 16 + fr][fq * 8]);
    f32x4 cb[4];
#pragma unroll
    for (int nf = 0; nf < 4; ++nf) {
        const half8 bfB = *reinterpret_cast<const half8*>(&Bsh[nf * 16 + fr][fq * 8]);
        f32x4 z = {0.f, 0.f, 0.f, 0.f};
        cb[nf] = __builtin_amdgcn_mfma_f32_16x16x32_f16(afC, bfB, z, 0, 0, 0);
    }
    // G = CB * exp(segsum)  (mask s<=l), store fp16
#pragma unroll
    for (int nf = 0; nf < 4; ++nf) {
        const int s = nf * 16 + fr;
        const float crs = cumr[s], sls = sl_[s], cls = cl_[s];
#pragma unroll
        for (int j = 0; j < 4; ++j) {
            const int l = w * 16 + fq * 4 + j;
            const float dr = fminf(cumr[l] - crs, 0.0f);
            const float e = __expf(dr);
            const float cd = cl_[l] * cls + sl_[l] * sls;
            const float sd = sl_[l] * cls - cl_[l] * sls;
            const float ge = (s <= l) ? cb[nf][j] * e : 0.0f;
            Gr[l][s] = (_Float16)(ge * cd);
            Gi[l][s] = (_Float16)(ge * sd);
        }
    }
    __syncthreads();

    // Y_diag = G @ xdt
    f32x4 accr[4], acci[4];
#pragma unroll
    for (int nf = 0; nf < 4; ++nf)
#pragma unroll
        for (int e = 0; e < 4; ++e) { accr[nf][e] = 0.f; acci[nf][e] = 0.f; }
#pragma unroll
    for (int ks = 0; ks < 64; ks += 32) {
        const half8 ar = *reinterpret_cast<const half8*>(&Gr[w * 16 + fr][ks + fq * 8]);
        const half8 ai = *reinterpret_cast<const half8*>(&Gi[w * 16 + fr][ks + fq * 8]);
#pragma unroll
        for (int nf = 0; nf < 4; ++nf) {
            const half8 bx = *reinterpret_cast<const half8*>(&Xt[nf * 16 + fr][ks + fq * 8]);
            accr[nf] = __builtin_amdgcn_mfma_f32_16x16x32_f16(ar, bx, accr[nf], 0, 0, 0);
            acci[nf] = __builtin_amdgcn_mfma_f32_16x16x32_f16(ai, bx, acci[nf], 0, 0, 0);
        }
    }
    // Y_off inner: O = C @ S^T
    f32x4 orr[4], oii[4];
#pragma unroll
    for (int nf = 0; nf < 4; ++nf) {
        const half8 br = *reinterpret_cast<const half8*>(&Srs[nf * 16 + fr][fq * 8]);
        const half8 bi = *reinterpret_cast<const half8*>(&Sis[nf * 16 + fr][fq * 8]);
        f32x4 z = {0.f, 0.f, 0.f, 0.f};
        orr[nf] = __builtin_amdgcn_mfma_f32_16x16x32_f16(afC, br, z, 0, 0, 0);
        oii[nf] = __builtin_amdgcn_mfma_f32_16x16x32_f16(afC, bi, z, 0, 0, 0);
    }

    // epilogue: Y = Ydiag + E*O; D residual; z-gate; fp16 store
    const float dcoef = Dp[2 * h];
#pragma unroll
    for (int nf = 0; nf < 4; ++nf) {
        const int p = nf * 16 + fr;
#pragma unroll
        for (int j = 0; j < 4; ++j) {
            const int l = w * 16 + fq * 4 + j;
            const int row = rowb + l;
            const float er = Er[l], ei = Ei[l];
            float yr = accr[nf][j] + er * orr[nf][j] - ei * oii[nf][j];
            float yi = acci[nf][j] + er * oii[nf][j] + ei * orr[nf][j];
            const float xinv = (float)conv[(size_t)row * CONVD + h * HDIM + p];
            yr = fmaf(xinv, dcoef, yr);
            const size_t zidx = (size_t)row * DIP + h * 128 + p;
            const float zr = (float)zx[zidx], zi2 = (float)zx[zidx + 64];
            const size_t aidx2 = (size_t)row * DZCOLS + h * 128 + p;
            A2[aidx2]      = (_Float16)(yr * clip6f(zr));
            A2[aidx2 + 64] = (_Float16)(yi * clip6f(zi2));
        }
    }
}

// ---------------------------------------------------------------------------
// K6: out[M,256](fp32) = (A2 * rms_scale_row) @ Wot^T, RMS fused; XCD swizzle
// ---------------------------------------------------------------------------
__global__ __launch_bounds__(256) void k_gemm_out(const _Float16* __restrict__ A,
                                                  const _Float16* __restrict__ Bt,
                                                  float* __restrict__ C)
{
    __shared__ _Float16 As[128][72];
    __shared__ _Float16 Bs[128][72];
    __shared__ float ssp[128][8];
    __shared__ float scl[128];
    const int t  = threadIdx.x;
    // nwg = 256 = 8 XCDs * 32; both n-blocks of an m-panel stay on one XCD
    const int orig = blockIdx.x;
    const int nid  = (orig & 7) * 32 + (orig >> 3);
    const int m0 = (nid >> 1) * 128;
    const int n0 = (nid & 1) * 128;
    const int lane = t & 63, wid = t >> 6;
    const int wr = wid >> 1, wc = wid & 1;
    const int fr = lane & 15, fq = lane >> 4;

    f32x4 acc[4][4];
#pragma unroll
    for (int m = 0; m < 4; ++m)
#pragma unroll
        for (int n = 0; n < 4; ++n)
#pragma unroll
            for (int e = 0; e < 4; ++e) acc[m][n][e] = 0.0f;
    float ss[4] = {0.f, 0.f, 0.f, 0.f};

    for (int kt = 0; kt < DZCOLS; kt += 64) {
#pragma unroll
        for (int q = 0; q < 4; ++q) {
            const int idx = t + q * 256;
            const int r = idx >> 3, ch = idx & 7;
            const half8 av = *reinterpret_cast<const half8*>(
                A + (size_t)(m0 + r) * DZCOLS + kt + ch * 8);
            *reinterpret_cast<half8*>(&As[r][ch * 8]) = av;
            float s = 0.f;
#pragma unroll
            for (int e = 0; e < 8; ++e) { const float f = (float)av[e]; s = fmaf(f, f, s); }
            ss[q] += s;
            *reinterpret_cast<s16x8*>(&Bs[r][ch * 8]) =
                *reinterpret_cast<const s16x8*>(Bt + (size_t)(n0 + r) * DZCOLS + kt + ch * 8);
        }
        __syncthreads();
#pragma unroll
        for (int ks = 0; ks < 64; ks += 32) {
            half8 af[4], bf[4];
#pragma unroll
            for (int m = 0; m < 4; ++m)
                af[m] = *reinterpret_cast<const half8*>(&As[wr * 64 + m * 16 + fr][ks + fq * 8]);
#pragma unroll
            for (int n = 0; n < 4; ++n)
                bf[n] = *reinterpret_cast<const half8*>(&Bs[wc * 64 + n * 16 + fr][ks + fq * 8]);
#pragma unroll
            for (int m = 0; m < 4; ++m)
#pragma unroll
                for (int n = 0; n < 4; ++n)
                    acc[m][n] = __builtin_amdgcn_mfma_f32_16x16x32_f16(af[m], bf[n], acc[m][n], 0, 0, 0);
        }
        __syncthreads();
    }

    // fused per-row RMS scale: thread t staged rows (t>>3)+q*32, cols ch=t&7
#pragma unroll
    for (int q = 0; q < 4; ++q) ssp[(t >> 3) + q * 32][t & 7] = ss[q];
    __syncthreads();
    if (t < 128) {
        float s = 0.f;
#pragma unroll
        for (int ch = 0; ch < 8; ++ch) s += ssp[t][ch];
        scl[t] = rsqrtf(s * (1.0f / 1024.0f) + 1e-5f);
    }
    __syncthreads();

#pragma unroll
    for (int m = 0; m < 4; ++m)
#pragma unroll
        for (int j = 0; j < 4; ++j) {
            const int rloc = wr * 64 + m * 16 + fq * 4 + j;
            const int row = m0 + rloc;
            const float sc = scl[rloc];
#pragma unroll
            for (int n = 0; n < 4; ++n) {
                const int col = n0 + wc * 64 + n * 16 + fr;
                C[(size_t)row * DMODEL + col] = acc[m][n][j] * sc;
            }
        }
}

// ---------------------------------------------------------------------------
extern "C" void kernel_launch(void* const* d_in, const int* in_sizes, int n_in,
                              void* d_out, int out_size, void* d_ws, size_t ws_size,
                              hipStream_t stream)
{
    const float* x         = (const float*)d_in[0];
    const float* W_in      = (const float*)d_in[1];
    const float* conv_w    = (const float*)d_in[2];
    const float* conv_b    = (const float*)d_in[3];
    const float* A_log     = (const float*)d_in[4];
    const float* dt_bias   = (const float*)d_in[5];
    const float* Dp        = (const float*)d_in[6];
    const float* init_conv = (const float*)d_in[7];
    const float* init_ssm  = (const float*)d_in[8];
    const float* norm_w    = (const float*)d_in[9];
    const float* W_out     = (const float*)d_in[10];
    float* out = (float*)d_out;

    // fp32 pool
    float* ws      = (float*)d_ws;
    float* dtraw   = ws;                                                       // M*8
    float* Acum    = dtraw + (size_t)MROWS * 8;                                // 262,144
    float* ctbuf   = Acum + (size_t)BATCHN * NHEADS * NCHUNK * CHK * 2;        // 4096
    float* stbuf   = ctbuf + (size_t)BATCHN * NHEADS * NCHUNK * 2;             // 4,194,304
    float* SinBuf  = stbuf + (size_t)BATCHN * NCHUNK * NHEADS * HDIM * DSTATE * 2;
    // fp16 pool
    _Float16* zx      = (_Float16*)(SinBuf + (size_t)BATCHN * NCHUNK * NHEADS * HDIM * DSTATE * 2);
    _Float16* convout = zx + (size_t)MROWS * DIP;
    _Float16* A2      = convout + (size_t)MROWS * CONVD;
    _Float16* Bt16    = A2 + (size_t)MROWS * DZCOLS;
    _Float16* Wot     = Bt16 + (size_t)NPAD * DMODEL;
    _Float16* A16     = Wot + (size_t)DMODEL * DZCOLS;                         // M*256 halves
    // total ~149 MB

    k_cvt_x<<<dim3(MROWS * DMODEL / 8 / 256), dim3(256), 0, stream>>>(x, A16);
    k_cvt_win<<<dim3(NPAD), dim3(256), 0, stream>>>(W_in, Bt16);
    k_cvt_wout<<<dim3(DZCOLS), dim3(256), 0, stream>>>(W_out, norm_w, Wot);

    k_gemm_in<<<dim3((NPAD / 128) * (MROWS / 128)), dim3(256), 0, stream>>>(
        A16, Bt16, zx, dtraw);

    const int convThreads = MROWS * (CONVD / 8);
    k_conv<<<(convThreads + 255) / 256, dim3(256), 0, stream>>>(
        zx, conv_w, conv_b, init_conv, convout);

    k_states<<<dim3(NCHUNK, NHEADS, BATCHN), dim3(256), 0, stream>>>(
        dtraw, convout, A_log, dt_bias, Acum, ctbuf, stbuf);

    k_scan<<<dim3(HDIM / 8, NHEADS, BATCHN), dim3(128), 0, stream>>>(
        ctbuf, stbuf, init_ssm, SinBuf);

    k_yout<<<dim3(NCHUNK, NHEADS, BATCHN), dim3(256), 0, stream>>>(
        convout, Acum, SinBuf, Dp, dt_bias, dtraw, zx, A2);

    k_gemm_out<<<dim3((DMODEL / 128) * (MROWS / 128)), dim3(256), 0, stream>>>(
        A2, Wot, out);
}